// Round 7
// baseline (6498.231 us; speedup 1.0000x reference)
//
#include <hip/hip_runtime.h>
#include <cmath>

// ---------------------------------------------------------------------------
// DeepAR sampling on MI355X. Round 16: decoder occupancy via half-tiles.
// r6/r15 landed 5006 us; fused head was ~neutral -> dec GEMM itself is 84
// us/step vs 16-19 us MFMA floor. r13 counters for this exact kernel body:
// MfmaUtil 12%, VALUBusy 17%, Occupancy 24%, HBM <3% = latency-bound at
// 2 blocks/CU (33KB LDS + 124 VGPR). FIX: halve the output tile ->
// 2048 blocks x (64 rows x 96 cols): accs 2x3 (-48 VGPR), LDS 16.6 KB ->
// natural occupancy ~4 blocks/CU = 2x waves/SIMD for latency hiding.
// BIT-IDENTICAL numerics: each output's K-chain is the same 16-step x 3-MFMA
// sequence; row-split changes no FP order (GEMM, gates, heads, RNG all
// unchanged). XCD mapping preserved (mb = xcd*16 + slot&15; same-A-tile
// blocks share one XCD's L2). launch_bounds(256,2) kept as floor only
// (r14 lesson: never force occupancy through the register allocator).
// Encoder/prep unchanged from r12 (773 us, 0 conflicts).
// ---------------------------------------------------------------------------

#define JAX_PARTITIONABLE 1

#define HIDDEN 512
#define EMB 40
#define HIST 336
#define PRED 48
#define S_N 8192
#define ENC_BLOCKS 48

#define HPLANE (8192 * 512)     // shorts per h split plane
#define WPLANE (1536 * 512)     // shorts per W split plane
#define INV4096 (1.0f / 4096.0f)

typedef __attribute__((ext_vector_type(8))) _Float16 half8;
typedef __attribute__((ext_vector_type(4))) float f32x4;

// ------------------------------- threefry ----------------------------------
struct KeyPair { unsigned a, b; };

__device__ __forceinline__ unsigned rotl32_(unsigned v, unsigned s) {
  return (v << s) | (v >> (32u - s));
}

__device__ __forceinline__ KeyPair tf2x32(KeyPair k, unsigned x0, unsigned x1) {
  unsigned ks0 = k.a, ks1 = k.b, ks2 = ks0 ^ ks1 ^ 0x1BD11BDAu;
  x0 += ks0; x1 += ks1;
#define TF_R(r) { x0 += x1; x1 = rotl32_(x1, r); x1 ^= x0; }
  TF_R(13u) TF_R(15u) TF_R(26u) TF_R(6u)  x0 += ks1; x1 += ks2 + 1u;
  TF_R(17u) TF_R(29u) TF_R(16u) TF_R(24u) x0 += ks2; x1 += ks0 + 2u;
  TF_R(13u) TF_R(15u) TF_R(26u) TF_R(6u)  x0 += ks0; x1 += ks1 + 3u;
  TF_R(17u) TF_R(29u) TF_R(16u) TF_R(24u) x0 += ks1; x1 += ks2 + 4u;
  TF_R(13u) TF_R(15u) TF_R(26u) TF_R(6u)  x0 += ks2; x1 += ks0 + 5u;
#undef TF_R
  KeyPair r; r.a = x0; r.b = x1; return r;
}

__device__ __forceinline__ void split2_(KeyPair key, KeyPair& r0, KeyPair& r1) {
#if JAX_PARTITIONABLE
  r0 = tf2x32(key, 0u, 0u);
  r1 = tf2x32(key, 0u, 1u);
#else
  KeyPair p0 = tf2x32(key, 0u, 2u);
  KeyPair p1 = tf2x32(key, 1u, 3u);
  r0.a = p0.a; r0.b = p1.a;
  r1.a = p0.b; r1.b = p1.b;
#endif
}

__device__ __forceinline__ void split3_(KeyPair key, KeyPair& r0, KeyPair& r1, KeyPair& r2) {
#if JAX_PARTITIONABLE
  r0 = tf2x32(key, 0u, 0u);
  r1 = tf2x32(key, 0u, 1u);
  r2 = tf2x32(key, 0u, 2u);
#else
  KeyPair p0 = tf2x32(key, 0u, 3u);
  KeyPair p1 = tf2x32(key, 1u, 4u);
  KeyPair p2 = tf2x32(key, 2u, 5u);
  r0.a = p0.a; r0.b = p1.a;
  r1.a = p2.a; r1.b = p0.b;
  r2.a = p1.b; r2.b = p2.b;
#endif
}

__device__ __forceinline__ unsigned scalar_bits_(KeyPair key) {
#if JAX_PARTITIONABLE
  KeyPair p = tf2x32(key, 0u, 0u);
  return p.a ^ p.b;
#else
  return tf2x32(key, 0u, 0u).a;
#endif
}

__device__ __forceinline__ unsigned batch_bits_8192_(KeyPair key, int s) {
#if JAX_PARTITIONABLE
  KeyPair p = tf2x32(key, 0u, (unsigned)s);
  return p.a ^ p.b;
#else
  if (s < 4096) return tf2x32(key, (unsigned)s, (unsigned)(4096 + s)).a;
  return tf2x32(key, (unsigned)(s - 4096), (unsigned)s).b;
#endif
}

__device__ __forceinline__ KeyPair subkey_of_8192_(KeyPair key, int s) {
#if JAX_PARTITIONABLE
  return tf2x32(key, 0u, (unsigned)s);
#else
  KeyPair r;
  if (s < 4096) {
    r.a = tf2x32(key, (unsigned)(2 * s),     (unsigned)(8192 + 2 * s)).a;
    r.b = tf2x32(key, (unsigned)(2 * s + 1), (unsigned)(8192 + 2 * s + 1)).a;
  } else {
    int m = 2 * s - 8192;
    r.a = tf2x32(key, (unsigned)m,       (unsigned)(m + 8192)).b;
    r.b = tf2x32(key, (unsigned)(m + 1), (unsigned)(m + 1 + 8192)).b;
  }
  return r;
#endif
}

// ------------------------- fp32 numerics (XLA-matched) ---------------------
__device__ __forceinline__ float acc_logf_(float x) {
  return (float)log((double)x);
}
__device__ __forceinline__ float acc_expf_(float x) {
  return (float)exp((double)x);
}

__device__ __forceinline__ float bits_to_uniform01_(unsigned bits) {
  return __uint_as_float((bits >> 9) | 0x3F800000u) - 1.0f;
}

__device__ __forceinline__ float xla_log1pf_(float t) {
  #pragma clang fp contract(off)
  float small_ = (1.0f + (-0.5f) * t) * t;
  float large_ = acc_logf_(t + 1.0f);
  return (fabsf(t) < 1e-4f) ? small_ : large_;
}

__device__ float xla_erfinv_(float x) {
  #pragma clang fp contract(off)
  float w = -xla_log1pf_(-(x * x));
  float p;
  if (w < 5.0f) {
    float ww = w - 2.5f;
    p = 2.81022636e-08f;
    p = 3.43273939e-07f + p * ww;
    p = -3.5233877e-06f + p * ww;
    p = -4.39150654e-06f + p * ww;
    p = 0.00021858087f + p * ww;
    p = -0.00125372503f + p * ww;
    p = -0.00417768164f + p * ww;
    p = 0.246640727f + p * ww;
    p = 1.50140941f + p * ww;
  } else {
    float ww = sqrtf(w) - 3.0f;
    p = -0.000200214257f;
    p = 0.000100950558f + p * ww;
    p = 0.00134934322f + p * ww;
    p = -0.00367342844f + p * ww;
    p = 0.00573950773f + p * ww;
    p = -0.0076224613f + p * ww;
    p = 0.00943887047f + p * ww;
    p = 1.00167406f + p * ww;
    p = 2.83297682f + p * ww;
  }
  return p * x;
}

__device__ float bits_to_normal_(unsigned bits) {
  #pragma clang fp contract(off)
  const float lo = __uint_as_float(0xBF7FFFFFu);
  float f = bits_to_uniform01_(bits);
  float u = f * 2.0f + lo;
  u = fmaxf(lo, u);
  return __uint_as_float(0x3FB504F3u) * xla_erfinv_(u);
}

__device__ __forceinline__ float softplus_(float x) {
  #pragma clang fp contract(off)
  float amax = fmaxf(x, 0.0f);
  float e = acc_expf_(-fabsf(x));
  return amax + xla_log1pf_(e);
}

__device__ __forceinline__ float sigmoid_(float v) { return 1.0f / (1.0f + expf(-v)); }

// fp16 split helpers (round-to-nearest-even via cast)
__device__ __forceinline__ unsigned short f2h_(float f) {
  _Float16 h = (_Float16)f;
  return __builtin_bit_cast(unsigned short, h);
}
__device__ __forceinline__ float h2f_(unsigned short b) {
  return (float)__builtin_bit_cast(_Float16, b);
}

// ------------------------- gamma / student-t sampler -----------------------
__device__ float gamma_sample_(KeyPair gkey, float alpha) {
  #pragma clang fp contract(off)
  const float third = 0.33333334f;
  float d = alpha - third;
  float c = third / sqrtf(d);
  KeyPair key, boost_sub;
  split2_(gkey, key, boost_sub);
  (void)boost_sub;
  float X = 0.0f, V = 1.0f, U = 2.0f;
  for (int guard = 0; guard < 1024; guard++) {
    float X2 = X * X;
    float sq = 1.0f - 0.0331f * (X2 * X2);
    bool cont = false;
    if (U >= sq) {
      float lhs = acc_logf_(U);
      float rhs = (X * 0.5f) + (d * ((1.0f - V) + acc_logf_(V)));
      cont = (lhs >= rhs);
    }
    if (!cont) break;
    KeyPair nkey, xkey, Ukey;
    split3_(key, nkey, xkey, Ukey);
    key = nkey;
    float x, v;
    KeyPair kk = xkey;
    do {
      KeyPair knew, sub;
      split2_(kk, knew, sub);
      kk = knew;
      x = bits_to_normal_(scalar_bits_(sub));
      v = 1.0f + x * c;
    } while (v <= 0.0f);
    X = x * x;
    V = (v * v) * v;
    U = bits_to_uniform01_(scalar_bits_(Ukey));
  }
  return d * V;
}

__device__ float sample_t_eps_(int k, int s, float df) {
  #pragma clang fp contract(off)
  KeyPair base; base.a = 0u; base.b = 42u;
  KeyPair tkey = tf2x32(base, 0u, (unsigned)k);
  KeyPair key_n, key_g;
  split2_(tkey, key_n, key_g);
  float n = bits_to_normal_(batch_bits_8192_(key_n, s));
  KeyPair gkey = subkey_of_8192_(key_g, s);
  float half_df = df * 0.5f;
  float g = gamma_sample_(gkey, half_df);
  return n * sqrtf(half_df / g);
}

// ------------------------------- kernels -----------------------------------

__global__ __launch_bounds__(256) void prep_kernel(
    const float* __restrict__ x, const float* __restrict__ x_mark,
    const float* __restrict__ y_mark, const float* __restrict__ W_emb,
    const float* __restrict__ b_emb, float* __restrict__ scale_p,
    float* __restrict__ tfe, float* __restrict__ emb_y,
    unsigned long long* __restrict__ gh2) {
  __shared__ float xs[HIST];
  int tid = threadIdx.x;
  for (int i = tid; i < HIST; i += 256) xs[i] = fabsf(x[i]);
  __syncthreads();
  if (tid == 0) {
    float s = 0.0f;
    for (int t = 0; t < HIST; t++) s += xs[t];
    float m = s / 336.0f;
    scale_p[0] = fmaxf(m, 1e-5f);
  }
  // zero tagged gh exchange buffer (both parities) -> re-poison safe
  for (int i = tid; i < 2 * 1536; i += 256) gh2[i] = 0ull;
  for (int idx = tid; idx < HIST * EMB; idx += 256) {
    int t = idx / EMB, e = idx % EMB;
    float a = b_emb[e];
    for (int f = 0; f < 4; f++) a += x_mark[t * 4 + f] * W_emb[e * 4 + f];
    tfe[idx] = a;
  }
  for (int idx = tid; idx < PRED * EMB; idx += 256) {
    int kk = idx / EMB, e = idx % EMB;
    float a = b_emb[e];
    for (int f = 0; f < 4; f++) a += y_mark[kk * 4 + f] * W_emb[e * 4 + f];
    emb_y[idx] = a;
  }
}

__global__ __launch_bounds__(256) void enc_gi_kernel(
    const float* __restrict__ x, const float* __restrict__ tfe,
    const float* __restrict__ W_ih, const float* __restrict__ b_ih,
    const float* __restrict__ scale_p, float* __restrict__ enc_gi) {
  __shared__ float fe[EMB];
  __shared__ float xs_s;
  int t = blockIdx.x;
  int tid = threadIdx.x;
  if (tid < EMB) fe[tid] = tfe[t * EMB + tid];
  if (tid == 0) xs_s = x[t] / scale_p[0];
  __syncthreads();
  float xs = xs_s;
  for (int r = tid; r < 3 * HIDDEN; r += 256) {
    const float* wr = W_ih + (size_t)r * 41;
    float a = b_ih[r] + wr[0] * xs;
    #pragma unroll
    for (int e = 0; e < EMB; e++) a += wr[1 + e] * fe[e];
    enc_gi[(size_t)t * 1536 + r] = a;
  }
}

__global__ __launch_bounds__(256) void giy_kernel(
    const float* __restrict__ emb_y, const float* __restrict__ W_ih,
    const float* __restrict__ b_ih, float* __restrict__ giy) {
  __shared__ float fe[EMB];
  int k = blockIdx.x;
  int tid = threadIdx.x;
  if (tid < EMB) fe[tid] = emb_y[k * EMB + tid];
  __syncthreads();
  for (int r = tid; r < 3 * HIDDEN; r += 256) {
    const float* wr = W_ih + (size_t)r * 41;
    float a = b_ih[r];
    #pragma unroll
    for (int e = 0; e < EMB; e++) a += wr[1 + e] * fe[e];
    giy[(size_t)k * 1536 + r] = a;
  }
}

// W_hh -> 2 fp16 split planes: Wr[sp][jb*96 + g*32 + jl][k], row = g*512+jb*32+jl
__global__ __launch_bounds__(256) void wsplit_kernel(
    const float* __restrict__ W_hh, unsigned short* __restrict__ Wr) {
  int row = blockIdx.x;                 // 0..1535
  int g = row >> 9;
  int jg = row & 511;
  int jb = jg >> 5, jl = jg & 31;
  size_t dst = ((size_t)jb * 96 + g * 32 + jl) * 512;
  for (int k = threadIdx.x; k < 512; k += 256) {
    float w = W_hh[(size_t)row * 512 + k];
    unsigned short g0 = f2h_(w);
    float r1 = (w - h2f_(g0)) * 4096.0f;
    unsigned short g1 = f2h_(r1);
    Wr[dst + k] = g0;
    Wr[WPLANE + dst + k] = g1;
  }
}

// split h_T (512) into sT[2][512] fp16 planes
__global__ __launch_bounds__(256) void hsplit_kernel(
    const float* __restrict__ h_T, unsigned short* __restrict__ sT) {
  int i = threadIdx.x;
  for (int j = i; j < 512; j += 256) {
    float v = h_T[j];
    unsigned short f0 = f2h_(v);
    float r1 = (v - h2f_(f0)) * 4096.0f;
    sT[j] = f0;
    sT[512 + j] = f2h_(r1);
  }
}

// broadcast sT rows into h2[2][8192][512]
__global__ __launch_bounds__(128) void h2bcast_kernel(
    const unsigned short* __restrict__ sT, unsigned short* __restrict__ h2) {
  int row = blockIdx.x;
  int tid = threadIdx.x;
  int sp = tid >> 6, c = tid & 63;
  ((uint4*)(h2 + (size_t)sp * HPLANE + (size_t)row * 512))[c] =
      ((const uint4*)(sT + sp * 512))[c];
}

// ---------------------------------------------------------------------------
// Persistent encoder GRU (r12, proven): tagged single-hop exchange, padded
// LDS (stride 68). Unchanged.
// ---------------------------------------------------------------------------
__device__ __forceinline__ int hpad_(int j) { return (j >> 6) * 68 + (j & 63); }

__global__ __launch_bounds__(256) void enc_gru_kernel(
    const float* __restrict__ enc_gi, const float* __restrict__ W_hh,
    const float* __restrict__ b_hh, unsigned long long* __restrict__ gh2,
    float* __restrict__ h_T) {
  __shared__ __align__(16) float hsb[2][544];
  int tid = threadIdx.x;
  int gtid = blockIdx.x * 256 + tid;
  int row = gtid >> 3;
  int sub = gtid & 7;

  float w[64];
  const float* wp = W_hh + (size_t)row * HIDDEN + sub * 64;
  #pragma unroll
  for (int i = 0; i < 16; i++) {
    float4 v = *(const float4*)(wp + 4 * i);
    w[4 * i + 0] = v.x; w[4 * i + 1] = v.y; w[4 * i + 2] = v.z; w[4 * i + 3] = v.w;
  }
  for (int i = tid; i < 544; i += 256) hsb[0][i] = 0.f;
  float bhr0 = b_hh[tid],       bhz0 = b_hh[512 + tid],  bhn0 = b_hh[1024 + tid];
  float bhr1 = b_hh[256 + tid], bhz1 = b_hh[768 + tid],  bhn1 = b_hh[1280 + tid];
  __syncthreads();

  for (int t = 0; t < HIST; t++) {
    int par = t & 1;
    unsigned tag = (unsigned)(t + 1);
    const float* hc = hsb[par];
    float* hw = hsb[par ^ 1];

    const float* gi = enc_gi + (size_t)t * 1536;
    float gir0 = gi[tid],        giz0 = gi[512 + tid],  gin0 = gi[1024 + tid];
    float gir1 = gi[256 + tid],  giz1 = gi[768 + tid],  gin1 = gi[1280 + tid];

    float p = 0.0f;
    const float4* hv = (const float4*)(hc + sub * 68);
    #pragma unroll
    for (int i = 0; i < 16; i++) {
      float4 v = hv[i];
      p += w[4 * i + 0] * v.x + w[4 * i + 1] * v.y +
           w[4 * i + 2] * v.z + w[4 * i + 3] * v.w;
    }
    p += __shfl_xor(p, 1, 64);
    p += __shfl_xor(p, 2, 64);
    p += __shfl_xor(p, 4, 64);
    if (sub == 0) {
      unsigned long long pk =
          ((unsigned long long)tag << 32) | (unsigned long long)__float_as_uint(p);
      __hip_atomic_store(&gh2[par * 1536 + row], pk, __ATOMIC_RELAXED,
                         __HIP_MEMORY_SCOPE_AGENT);
    }

    const unsigned long long* g = gh2 + par * 1536;
    unsigned long long v0, v1, v2, v3, v4, v5;
    for (;;) {
      v0 = __hip_atomic_load(&g[tid],         __ATOMIC_RELAXED, __HIP_MEMORY_SCOPE_AGENT);
      v1 = __hip_atomic_load(&g[512 + tid],   __ATOMIC_RELAXED, __HIP_MEMORY_SCOPE_AGENT);
      v2 = __hip_atomic_load(&g[1024 + tid],  __ATOMIC_RELAXED, __HIP_MEMORY_SCOPE_AGENT);
      v3 = __hip_atomic_load(&g[256 + tid],   __ATOMIC_RELAXED, __HIP_MEMORY_SCOPE_AGENT);
      v4 = __hip_atomic_load(&g[768 + tid],   __ATOMIC_RELAXED, __HIP_MEMORY_SCOPE_AGENT);
      v5 = __hip_atomic_load(&g[1280 + tid],  __ATOMIC_RELAXED, __HIP_MEMORY_SCOPE_AGENT);
      if ((unsigned)(v0 >> 32) == tag && (unsigned)(v1 >> 32) == tag &&
          (unsigned)(v2 >> 32) == tag && (unsigned)(v3 >> 32) == tag &&
          (unsigned)(v4 >> 32) == tag && (unsigned)(v5 >> 32) == tag)
        break;
      __builtin_amdgcn_s_sleep(1);
    }

    {
      float ghr = __uint_as_float((unsigned)v0);
      float ghz = __uint_as_float((unsigned)v1);
      float ghn = __uint_as_float((unsigned)v2);
      float r = sigmoid_(gir0 + (ghr + bhr0));
      float z = sigmoid_(giz0 + (ghz + bhz0));
      float n = tanhf(gin0 + r * (ghn + bhn0));
      hw[hpad_(tid)] = (1.0f - z) * n + z * hc[hpad_(tid)];
    }
    {
      float ghr = __uint_as_float((unsigned)v3);
      float ghz = __uint_as_float((unsigned)v4);
      float ghn = __uint_as_float((unsigned)v5);
      float r = sigmoid_(gir1 + (ghr + bhr1));
      float z = sigmoid_(giz1 + (ghz + bhz1));
      float n = tanhf(gin1 + r * (ghn + bhn1));
      hw[hpad_(tid + 256)] = (1.0f - z) * n + z * hc[hpad_(tid + 256)];
    }
    __syncthreads();
  }
  if (blockIdx.x == 0) {
    h_T[tid] = hsb[0][hpad_(tid)];
    h_T[tid + 256] = hsb[0][hpad_(tid + 256)];
  }
}

// head prologue: bit-identical to r12 dec_head math; redundant per block.
// Block covers 64 samples (its own mb tile); 16x redundancy across jb.
__device__ void head_prologue_(
    int mb, int jb, int tid, int kk, const float* __restrict__ partials_prev,
    const float* __restrict__ b_df, const float* __restrict__ b_loc,
    const float* __restrict__ b_sc, const float* __restrict__ scale_p,
    float* __restrict__ out, float* __restrict__ tgLds) {
  #pragma clang fp contract(off)
  if (tid < 64) {
    int s = mb * 64 + tid;
    const float* pp = partials_prev + (size_t)s * 48;
    float adf = 0.f, alo = 0.f, asc = 0.f;
    #pragma unroll
    for (int jbx = 0; jbx < 16; jbx++) {
      adf += pp[jbx * 3 + 0];
      alo += pp[jbx * 3 + 1];
      asc += pp[jbx * 3 + 2];
    }
    float df = 2.0f + softplus_(adf + b_df[0]);
    float loc = alo + b_loc[0];
    float sc = softplus_(asc + b_sc[0]);
    float eps = sample_t_eps_(kk, s, df);
    float smp = (loc + sc * eps) * scale_p[0];
    tgLds[tid] = smp;
    if (jb == 0) out[(size_t)s * PRED + kk] = smp;
  }
}

// ---------------------------------------------------------------------------
// Decoder GRU step via fp16 MFMA, half tile: 2048 blocks x (64 rows x 96
// cols). Same per-output K-chain as r9/r12 (bit-identical). Fused redundant
// head prologue. launch_bounds(256,2) floor; natural occupancy ~4 blocks/CU.
// ---------------------------------------------------------------------------
__global__ __launch_bounds__(256, 2) void dec_fused_kernel(
    const unsigned short* __restrict__ h2_in,   // [2][8192][512] fp16
    const unsigned short* __restrict__ Wr,      // [2][16 jb][96][512] fp16
    const float* __restrict__ giy_k, const float* __restrict__ b_hh,
    const float* __restrict__ W_ih, const float* __restrict__ x, int k,
    unsigned short* __restrict__ h2_out,
    const float* __restrict__ W_df, const float* __restrict__ W_loc,
    const float* __restrict__ W_sc,
    const float* __restrict__ partials_prev, float* __restrict__ partials_out,
    const float* __restrict__ b_df, const float* __restrict__ b_loc,
    const float* __restrict__ b_sc, const float* __restrict__ scale_p,
    float* __restrict__ out) {
  __shared__ unsigned short As[2][2][64][32];   // [buf][plane][row][col]
  __shared__ float tgLds[64];
  int b_ = blockIdx.x;
  int xcd = b_ & 7, slot = b_ >> 3;          // slot 0..255
  int mb = xcd * 16 + (slot & 15);           // 0..127 (64-row tiles)
  int jb = slot >> 4;                        // 0..15
  int tid = threadIdx.x;
  int lane = tid & 63;
  int wave = tid >> 6;
  int wm = wave >> 1, wn = wave & 1;
  int s0 = mb * 64;
  int q = lane >> 4, c = lane & 15;

  // fused heads for step k-1 (reads prev-parity partials; no cross-block dep)
  if (k > 0)
    head_prologue_(mb, jb, tid, k - 1, partials_prev, b_df, b_loc, b_sc,
                   scale_p, out, tgLds);
  float xlast = x[HIST - 1];

  f32x4 accm[2][3], accc[2][3];
  #pragma unroll
  for (int i = 0; i < 2; i++)
    #pragma unroll
    for (int g = 0; g < 3; g++) {
      accm[i][g] = (f32x4){0.f, 0.f, 0.f, 0.f};
      accc[i][g] = (f32x4){0.f, 0.f, 0.f, 0.f};
    }

  float hold[2][4];
  #pragma unroll
  for (int i = 0; i < 2; i++)
    #pragma unroll
    for (int r = 0; r < 4; r++) hold[i][r] = 0.f;

  // per-thread A staging map (2 chunks covering 2 planes x 64 rows x 32 cols)
  int asp[2], arow[2], acol[2];
  #pragma unroll
  for (int r = 0; r < 2; r++) {
    int a = r * 256 + tid;
    asp[r] = a >> 8;
    int rem = a & 255;
    arow[r] = rem >> 2;
    acol[r] = rem & 3;
  }

  // B-frag base address (row jb*96 + g*32 + wn*16 + c, col chunk q)
  const unsigned short* Bbase =
      Wr + ((size_t)jb * 96 + wn * 16 + c) * 512 + q * 8;

  // initial stage A (kb=0) into buffer 0
  #pragma unroll
  for (int r = 0; r < 2; r++) {
    uint4 v = *(const uint4*)(h2_in + (size_t)asp[r] * HPLANE +
                              (size_t)(s0 + arow[r]) * 512 + acol[r] * 8);
    *(uint4*)&As[0][asp[r]][arow[r]][(acol[r] ^ (arow[r] & 3)) * 8] = v;
  }
  // initial B (kb=0)
  half8 Bcur[3][2];
  #pragma unroll
  for (int g = 0; g < 3; g++) {
    Bcur[g][0] = *(const half8*)(Bbase + (size_t)g * 32 * 512);
    Bcur[g][1] = *(const half8*)(Bbase + WPLANE + (size_t)g * 32 * 512);
  }
  __syncthreads();

  int cur = 0;
  for (int kbi = 0; kbi < 16; kbi++) {
    int kb = kbi * 32;
    // prefetch next A + B
    uint4 Areg[2];
    half8 Bn[3][2];
    if (kbi < 15) {
      #pragma unroll
      for (int r = 0; r < 2; r++)
        Areg[r] = *(const uint4*)(h2_in + (size_t)asp[r] * HPLANE +
                                  (size_t)(s0 + arow[r]) * 512 + kb + 32 +
                                  acol[r] * 8);
      #pragma unroll
      for (int g = 0; g < 3; g++) {
        Bn[g][0] = *(const half8*)(Bbase + (size_t)g * 32 * 512 + kb + 32);
        Bn[g][1] = *(const half8*)(Bbase + WPLANE + (size_t)g * 32 * 512 + kb + 32);
      }
    }
    // capture h_old while its k-slice sits in LDS
    if (kbi == jb) {
      int cc = wn * 16 + c;
      #pragma unroll
      for (int i = 0; i < 2; i++)
        #pragma unroll
        for (int reg = 0; reg < 4; reg++) {
          int m = wm * 32 + i * 16 + q * 4 + reg;
          int idx = (((cc >> 3) ^ (m & 3)) << 3) + (cc & 7);
          hold[i][reg] = h2f_(As[cur][0][m][idx]) +
                         h2f_(As[cur][1][m][idx]) * INV4096;
        }
    }
    // compute (same per-output K-chain as r9)
    #pragma unroll
    for (int i = 0; i < 2; i++) {
      int m = wm * 32 + i * 16 + c;
      half8 a0 = *(const half8*)&As[cur][0][m][(q ^ (c & 3)) * 8];
      half8 a1 = *(const half8*)&As[cur][1][m][(q ^ (c & 3)) * 8];
      #pragma unroll
      for (int g = 0; g < 3; g++) {
        accm[i][g] = __builtin_amdgcn_mfma_f32_16x16x32_f16(a0, Bcur[g][0], accm[i][g], 0, 0, 0);
        accc[i][g] = __builtin_amdgcn_mfma_f32_16x16x32_f16(a0, Bcur[g][1], accc[i][g], 0, 0, 0);
        accc[i][g] = __builtin_amdgcn_mfma_f32_16x16x32_f16(a1, Bcur[g][0], accc[i][g], 0, 0, 0);
      }
    }
    // store prefetched A into the other buffer
    if (kbi < 15) {
      #pragma unroll
      for (int r = 0; r < 2; r++)
        *(uint4*)&As[cur ^ 1][asp[r]][arow[r]][(acol[r] ^ (arow[r] & 3)) * 8] =
            Areg[r];
      #pragma unroll
      for (int g = 0; g < 3; g++) {
        Bcur[g][0] = Bn[g][0];
        Bcur[g][1] = Bn[g][1];
      }
    }
    __syncthreads();
    cur ^= 1;
  }

  // epilogue: gates + h update + nt fp16 2-split store + head partials
  float* pb = (float*)&As[0][0][0][0];   // reuse LDS: 4 waves x 32 x 3 floats
  {
    int j = jb * 32 + wn * 16 + c;
    float gyr = giy_k[j], gyz = giy_k[512 + j], gyn = giy_k[1024 + j];
    float w0r = W_ih[(size_t)j * 41];
    float w0z = W_ih[(size_t)(512 + j) * 41];
    float w0n = W_ih[(size_t)(1024 + j) * 41];
    float bhr = b_hh[j], bhz = b_hh[512 + j], bhn = b_hh[1024 + j];
    float wdj = W_df[j], wlj = W_loc[j], wsj = W_sc[j];
    #pragma unroll
    for (int i = 0; i < 2; i++) {
      #pragma unroll
      for (int reg = 0; reg < 4; reg++) {
        int s = s0 + wm * 32 + i * 16 + q * 4 + reg;
        float tg = (k == 0) ? xlast : tgLds[wm * 32 + i * 16 + q * 4 + reg];
        size_t off = (size_t)s * 512 + j;
        float h_old = hold[i][reg];
        float ghr = accm[i][0][reg] + accc[i][0][reg] * INV4096;
        float ghz = accm[i][1][reg] + accc[i][1][reg] * INV4096;
        float ghn = accm[i][2][reg] + accc[i][2][reg] * INV4096;
        float gr = (gyr + w0r * tg) + (ghr + bhr);
        float gz = (gyz + w0z * tg) + (ghz + bhz);
        float gn_i = gyn + w0n * tg;
        float gn_h = ghn + bhn;
        float r_ = sigmoid_(gr);
        float z_ = sigmoid_(gz);
        float n_ = tanhf(gn_i + r_ * gn_h);
        float hn = (1.0f - z_) * n_ + z_ * h_old;
        unsigned short f0 = f2h_(hn);
        float r1 = (hn - h2f_(f0)) * 4096.0f;
        __builtin_nontemporal_store(f0, &h2_out[off]);
        __builtin_nontemporal_store(f2h_(r1), &h2_out[HPLANE + off]);
        // head partial products (exact fp32 h), reduce over the 16 c-lanes
        float vd = hn * wdj, vl = hn * wlj, vs = hn * wsj;
        #pragma unroll
        for (int o = 1; o < 16; o <<= 1) {
          vd += __shfl_xor(vd, o, 64);
          vl += __shfl_xor(vl, o, 64);
          vs += __shfl_xor(vs, o, 64);
        }
        if (c == 0) {
          int sl = i * 16 + q * 4 + reg;               // 0..31
          int bix = ((wm * 2 + wn) * 32 + sl) * 3;
          pb[bix + 0] = vd; pb[bix + 1] = vl; pb[bix + 2] = vs;
        }
      }
    }
  }
  __syncthreads();
  // cross-wn add (fixed order: wn0 + wn1) + global partial store
  if (tid < 64) {
    int wmh = tid >> 5, sl = tid & 31;
    int ia = (wmh * 2 + 0) * 96 + sl * 3;
    int ib = ia + 96;
    int s = s0 + wmh * 32 + sl;
    size_t pofs = (size_t)s * 48 + jb * 3;
    partials_out[pofs + 0] = pb[ia + 0] + pb[ib + 0];
    partials_out[pofs + 1] = pb[ia + 1] + pb[ib + 1];
    partials_out[pofs + 2] = pb[ia + 2] + pb[ib + 2];
  }
}

// final heads (k = PRED-1): same math as head prologue, writes out only.
__global__ __launch_bounds__(64) void dec_head_final(
    const float* __restrict__ partials, const float* __restrict__ b_df,
    const float* __restrict__ b_loc, const float* __restrict__ b_sc,
    const float* __restrict__ scale_p, float* __restrict__ out) {
  #pragma clang fp contract(off)
  int s = blockIdx.x * 64 + threadIdx.x;
  const float* p = partials + (size_t)s * 48;
  float adf = 0.f, alo = 0.f, asc = 0.f;
  #pragma unroll
  for (int jb = 0; jb < 16; jb++) {
    adf += p[jb * 3 + 0];
    alo += p[jb * 3 + 1];
    asc += p[jb * 3 + 2];
  }
  float df = 2.0f + softplus_(adf + b_df[0]);
  float loc = alo + b_loc[0];
  float sc = softplus_(asc + b_sc[0]);
  float eps = sample_t_eps_(PRED - 1, s, df);
  float smp = (loc + sc * eps) * scale_p[0];
  out[(size_t)s * PRED + (PRED - 1)] = smp;
}

// ------------------------------- launcher ----------------------------------
extern "C" void kernel_launch(void* const* d_in, const int* in_sizes, int n_in,
                              void* d_out, int out_size, void* d_ws, size_t ws_size,
                              hipStream_t stream) {
  const float* x      = (const float*)d_in[0];
  const float* x_mark = (const float*)d_in[1];
  const float* y_mark = (const float*)d_in[2];
  const float* W_emb  = (const float*)d_in[4];
  const float* b_emb  = (const float*)d_in[5];
  const float* W_ih   = (const float*)d_in[6];
  const float* W_hh   = (const float*)d_in[7];
  const float* b_ih   = (const float*)d_in[8];
  const float* b_hh   = (const float*)d_in[9];
  const float* W_df   = (const float*)d_in[10];
  const float* b_df   = (const float*)d_in[11];
  const float* W_loc  = (const float*)d_in[12];
  const float* b_loc  = (const float*)d_in[13];
  const float* W_sc   = (const float*)d_in[14];
  const float* b_sc   = (const float*)d_in[15];
  float* out = (float*)d_out;

  float* w = (float*)d_ws;
  unsigned short* h2_a = (unsigned short*)(w);                 // 2*8192*512 sh
  unsigned short* h2_b = (unsigned short*)(w + 4194304);       // 2*8192*512 sh
  unsigned short* Wr   = (unsigned short*)(w + 8388608);       // 2*1536*512 sh
  float* enc_gi = w + 9175040;              // 336*1536 (dead after encoder)
  float* giy    = w + 9691136;              // 48*1536
  float* tfe    = w + 9764864;              // 336*40
  float* emb_y  = w + 9778304;              // 48*40
  unsigned long long* gh2 = (unsigned long long*)(w + 9780224); // 2*1536 u64
  float* h_T    = w + 9786368;              // 512
  unsigned short* sT = (unsigned short*)(w + 9786880);  // 2*512 sh
  float* scale_p = w + 9795584;             // 1
  float* partials0 = w + 9795588;           // 8192*48 floats (~1.57 MB)
  float* partials1 = enc_gi;                // aliases dead enc_gi (2.06 MB)

  prep_kernel<<<1, 256, 0, stream>>>(x, x_mark, y_mark, W_emb, b_emb,
                                     scale_p, tfe, emb_y, gh2);
  enc_gi_kernel<<<HIST, 256, 0, stream>>>(x, tfe, W_ih, b_ih, scale_p, enc_gi);
  giy_kernel<<<PRED, 256, 0, stream>>>(emb_y, W_ih, b_ih, giy);
  wsplit_kernel<<<1536, 256, 0, stream>>>(W_hh, Wr);
  enc_gru_kernel<<<ENC_BLOCKS, 256, 0, stream>>>(enc_gi, W_hh, b_hh, gh2, h_T);
  hsplit_kernel<<<1, 256, 0, stream>>>(h_T, sT);
  h2bcast_kernel<<<S_N, 128, 0, stream>>>(sT, h2_a);

  for (int k = 0; k < PRED; k++) {
    const unsigned short* h_in = (k & 1) ? h2_b : h2_a;
    unsigned short* h_o = (k & 1) ? h2_a : h2_b;
    const float* pprev = (k & 1) ? partials0 : partials1;  // (k-1)&1 parity
    float* pcur = (k & 1) ? partials1 : partials0;         // k&1 parity
    dec_fused_kernel<<<2048, 256, 0, stream>>>(
        h_in, Wr, giy + (size_t)k * 1536, b_hh, W_ih, x, k, h_o,
        W_df, W_loc, W_sc, pprev, pcur, b_df, b_loc, b_sc, scale_p, out);
  }
  // final column: heads for k = PRED-1 (partials parity 47&1 == 1)
  dec_head_final<<<S_N / 64, 64, 0, stream>>>(partials1, b_df, b_loc, b_sc,
                                              scale_p, out);
}

// Round 9
// 5085.622 us; speedup vs baseline: 1.2778x; 1.2778x over previous
//
#include <hip/hip_runtime.h>
#include <cmath>

// ---------------------------------------------------------------------------
// DeepAR sampling on MI355X. Round 18: resubmit r17 (infra flake retry).
// r17 ("container failed twice") showed no kernel-attributable failure:
// both deltas audited in-bounds, spin-free, deadlock-impossible. Timing
// blocks this session show heavy infra flakiness (70s pushes, 24s acquires).
// Re-measuring the same kernel:
//  (1) initial A-stage on waves 2-3 only (8 chunks/thread, same addresses/
//      values as r6's all-thread stage) -> overlaps waves 0-1's fused-head
//      RNG (f64 log/exp heavy) instead of serializing behind it.
//  (2) hsplit folded into enc_gru block-0 tail (writes sT directly; same
//      math) -> one fewer launch, h_T round trip dropped.
// Everything else bit-identical to r6/r15 (proven 5006 us, absmax 1.492188).
// ---------------------------------------------------------------------------

#define JAX_PARTITIONABLE 1

#define HIDDEN 512
#define EMB 40
#define HIST 336
#define PRED 48
#define S_N 8192
#define ENC_BLOCKS 48

#define HPLANE (8192 * 512)     // shorts per h split plane
#define WPLANE (1536 * 512)     // shorts per W split plane
#define INV4096 (1.0f / 4096.0f)

typedef __attribute__((ext_vector_type(8))) _Float16 half8;
typedef __attribute__((ext_vector_type(4))) float f32x4;

// ------------------------------- threefry ----------------------------------
struct KeyPair { unsigned a, b; };

__device__ __forceinline__ unsigned rotl32_(unsigned v, unsigned s) {
  return (v << s) | (v >> (32u - s));
}

__device__ __forceinline__ KeyPair tf2x32(KeyPair k, unsigned x0, unsigned x1) {
  unsigned ks0 = k.a, ks1 = k.b, ks2 = ks0 ^ ks1 ^ 0x1BD11BDAu;
  x0 += ks0; x1 += ks1;
#define TF_R(r) { x0 += x1; x1 = rotl32_(x1, r); x1 ^= x0; }
  TF_R(13u) TF_R(15u) TF_R(26u) TF_R(6u)  x0 += ks1; x1 += ks2 + 1u;
  TF_R(17u) TF_R(29u) TF_R(16u) TF_R(24u) x0 += ks2; x1 += ks0 + 2u;
  TF_R(13u) TF_R(15u) TF_R(26u) TF_R(6u)  x0 += ks0; x1 += ks1 + 3u;
  TF_R(17u) TF_R(29u) TF_R(16u) TF_R(24u) x0 += ks1; x1 += ks2 + 4u;
  TF_R(13u) TF_R(15u) TF_R(26u) TF_R(6u)  x0 += ks2; x1 += ks0 + 5u;
#undef TF_R
  KeyPair r; r.a = x0; r.b = x1; return r;
}

__device__ __forceinline__ void split2_(KeyPair key, KeyPair& r0, KeyPair& r1) {
#if JAX_PARTITIONABLE
  r0 = tf2x32(key, 0u, 0u);
  r1 = tf2x32(key, 0u, 1u);
#else
  KeyPair p0 = tf2x32(key, 0u, 2u);
  KeyPair p1 = tf2x32(key, 1u, 3u);
  r0.a = p0.a; r0.b = p1.a;
  r1.a = p0.b; r1.b = p1.b;
#endif
}

__device__ __forceinline__ void split3_(KeyPair key, KeyPair& r0, KeyPair& r1, KeyPair& r2) {
#if JAX_PARTITIONABLE
  r0 = tf2x32(key, 0u, 0u);
  r1 = tf2x32(key, 0u, 1u);
  r2 = tf2x32(key, 0u, 2u);
#else
  KeyPair p0 = tf2x32(key, 0u, 3u);
  KeyPair p1 = tf2x32(key, 1u, 4u);
  KeyPair p2 = tf2x32(key, 2u, 5u);
  r0.a = p0.a; r0.b = p1.a;
  r1.a = p2.a; r1.b = p0.b;
  r2.a = p1.b; r2.b = p2.b;
#endif
}

__device__ __forceinline__ unsigned scalar_bits_(KeyPair key) {
#if JAX_PARTITIONABLE
  KeyPair p = tf2x32(key, 0u, 0u);
  return p.a ^ p.b;
#else
  return tf2x32(key, 0u, 0u).a;
#endif
}

__device__ __forceinline__ unsigned batch_bits_8192_(KeyPair key, int s) {
#if JAX_PARTITIONABLE
  KeyPair p = tf2x32(key, 0u, (unsigned)s);
  return p.a ^ p.b;
#else
  if (s < 4096) return tf2x32(key, (unsigned)s, (unsigned)(4096 + s)).a;
  return tf2x32(key, (unsigned)(s - 4096), (unsigned)s).b;
#endif
}

__device__ __forceinline__ KeyPair subkey_of_8192_(KeyPair key, int s) {
#if JAX_PARTITIONABLE
  return tf2x32(key, 0u, (unsigned)s);
#else
  KeyPair r;
  if (s < 4096) {
    r.a = tf2x32(key, (unsigned)(2 * s),     (unsigned)(8192 + 2 * s)).a;
    r.b = tf2x32(key, (unsigned)(2 * s + 1), (unsigned)(8192 + 2 * s + 1)).a;
  } else {
    int m = 2 * s - 8192;
    r.a = tf2x32(key, (unsigned)m,       (unsigned)(m + 8192)).b;
    r.b = tf2x32(key, (unsigned)(m + 1), (unsigned)(m + 1 + 8192)).b;
  }
  return r;
#endif
}

// ------------------------- fp32 numerics (XLA-matched) ---------------------
__device__ __forceinline__ float acc_logf_(float x) {
  return (float)log((double)x);
}
__device__ __forceinline__ float acc_expf_(float x) {
  return (float)exp((double)x);
}

__device__ __forceinline__ float bits_to_uniform01_(unsigned bits) {
  return __uint_as_float((bits >> 9) | 0x3F800000u) - 1.0f;
}

__device__ __forceinline__ float xla_log1pf_(float t) {
  #pragma clang fp contract(off)
  float small_ = (1.0f + (-0.5f) * t) * t;
  float large_ = acc_logf_(t + 1.0f);
  return (fabsf(t) < 1e-4f) ? small_ : large_;
}

__device__ float xla_erfinv_(float x) {
  #pragma clang fp contract(off)
  float w = -xla_log1pf_(-(x * x));
  float p;
  if (w < 5.0f) {
    float ww = w - 2.5f;
    p = 2.81022636e-08f;
    p = 3.43273939e-07f + p * ww;
    p = -3.5233877e-06f + p * ww;
    p = -4.39150654e-06f + p * ww;
    p = 0.00021858087f + p * ww;
    p = -0.00125372503f + p * ww;
    p = -0.00417768164f + p * ww;
    p = 0.246640727f + p * ww;
    p = 1.50140941f + p * ww;
  } else {
    float ww = sqrtf(w) - 3.0f;
    p = -0.000200214257f;
    p = 0.000100950558f + p * ww;
    p = 0.00134934322f + p * ww;
    p = -0.00367342844f + p * ww;
    p = 0.00573950773f + p * ww;
    p = -0.0076224613f + p * ww;
    p = 0.00943887047f + p * ww;
    p = 1.00167406f + p * ww;
    p = 2.83297682f + p * ww;
  }
  return p * x;
}

__device__ float bits_to_normal_(unsigned bits) {
  #pragma clang fp contract(off)
  const float lo = __uint_as_float(0xBF7FFFFFu);
  float f = bits_to_uniform01_(bits);
  float u = f * 2.0f + lo;
  u = fmaxf(lo, u);
  return __uint_as_float(0x3FB504F3u) * xla_erfinv_(u);
}

__device__ __forceinline__ float softplus_(float x) {
  #pragma clang fp contract(off)
  float amax = fmaxf(x, 0.0f);
  float e = acc_expf_(-fabsf(x));
  return amax + xla_log1pf_(e);
}

__device__ __forceinline__ float sigmoid_(float v) { return 1.0f / (1.0f + expf(-v)); }

// fp16 split helpers (round-to-nearest-even via cast)
__device__ __forceinline__ unsigned short f2h_(float f) {
  _Float16 h = (_Float16)f;
  return __builtin_bit_cast(unsigned short, h);
}
__device__ __forceinline__ float h2f_(unsigned short b) {
  return (float)__builtin_bit_cast(_Float16, b);
}

// ------------------------- gamma / student-t sampler -----------------------
__device__ float gamma_sample_(KeyPair gkey, float alpha) {
  #pragma clang fp contract(off)
  const float third = 0.33333334f;
  float d = alpha - third;
  float c = third / sqrtf(d);
  KeyPair key, boost_sub;
  split2_(gkey, key, boost_sub);
  (void)boost_sub;
  float X = 0.0f, V = 1.0f, U = 2.0f;
  for (int guard = 0; guard < 1024; guard++) {
    float X2 = X * X;
    float sq = 1.0f - 0.0331f * (X2 * X2);
    bool cont = false;
    if (U >= sq) {
      float lhs = acc_logf_(U);
      float rhs = (X * 0.5f) + (d * ((1.0f - V) + acc_logf_(V)));
      cont = (lhs >= rhs);
    }
    if (!cont) break;
    KeyPair nkey, xkey, Ukey;
    split3_(key, nkey, xkey, Ukey);
    key = nkey;
    float x, v;
    KeyPair kk = xkey;
    do {
      KeyPair knew, sub;
      split2_(kk, knew, sub);
      kk = knew;
      x = bits_to_normal_(scalar_bits_(sub));
      v = 1.0f + x * c;
    } while (v <= 0.0f);
    X = x * x;
    V = (v * v) * v;
    U = bits_to_uniform01_(scalar_bits_(Ukey));
  }
  return d * V;
}

__device__ float sample_t_eps_(int k, int s, float df) {
  #pragma clang fp contract(off)
  KeyPair base; base.a = 0u; base.b = 42u;
  KeyPair tkey = tf2x32(base, 0u, (unsigned)k);
  KeyPair key_n, key_g;
  split2_(tkey, key_n, key_g);
  float n = bits_to_normal_(batch_bits_8192_(key_n, s));
  KeyPair gkey = subkey_of_8192_(key_g, s);
  float half_df = df * 0.5f;
  float g = gamma_sample_(gkey, half_df);
  return n * sqrtf(half_df / g);
}

// ------------------------------- kernels -----------------------------------

__global__ __launch_bounds__(256) void prep_kernel(
    const float* __restrict__ x, const float* __restrict__ x_mark,
    const float* __restrict__ y_mark, const float* __restrict__ W_emb,
    const float* __restrict__ b_emb, float* __restrict__ scale_p,
    float* __restrict__ tfe, float* __restrict__ emb_y,
    unsigned long long* __restrict__ gh2) {
  __shared__ float xs[HIST];
  int tid = threadIdx.x;
  for (int i = tid; i < HIST; i += 256) xs[i] = fabsf(x[i]);
  __syncthreads();
  if (tid == 0) {
    float s = 0.0f;
    for (int t = 0; t < HIST; t++) s += xs[t];
    float m = s / 336.0f;
    scale_p[0] = fmaxf(m, 1e-5f);
  }
  // zero tagged gh exchange buffer (both parities) -> re-poison safe
  for (int i = tid; i < 2 * 1536; i += 256) gh2[i] = 0ull;
  for (int idx = tid; idx < HIST * EMB; idx += 256) {
    int t = idx / EMB, e = idx % EMB;
    float a = b_emb[e];
    for (int f = 0; f < 4; f++) a += x_mark[t * 4 + f] * W_emb[e * 4 + f];
    tfe[idx] = a;
  }
  for (int idx = tid; idx < PRED * EMB; idx += 256) {
    int kk = idx / EMB, e = idx % EMB;
    float a = b_emb[e];
    for (int f = 0; f < 4; f++) a += y_mark[kk * 4 + f] * W_emb[e * 4 + f];
    emb_y[idx] = a;
  }
}

__global__ __launch_bounds__(256) void enc_gi_kernel(
    const float* __restrict__ x, const float* __restrict__ tfe,
    const float* __restrict__ W_ih, const float* __restrict__ b_ih,
    const float* __restrict__ scale_p, float* __restrict__ enc_gi) {
  __shared__ float fe[EMB];
  __shared__ float xs_s;
  int t = blockIdx.x;
  int tid = threadIdx.x;
  if (tid < EMB) fe[tid] = tfe[t * EMB + tid];
  if (tid == 0) xs_s = x[t] / scale_p[0];
  __syncthreads();
  float xs = xs_s;
  for (int r = tid; r < 3 * HIDDEN; r += 256) {
    const float* wr = W_ih + (size_t)r * 41;
    float a = b_ih[r] + wr[0] * xs;
    #pragma unroll
    for (int e = 0; e < EMB; e++) a += wr[1 + e] * fe[e];
    enc_gi[(size_t)t * 1536 + r] = a;
  }
}

__global__ __launch_bounds__(256) void giy_kernel(
    const float* __restrict__ emb_y, const float* __restrict__ W_ih,
    const float* __restrict__ b_ih, float* __restrict__ giy) {
  __shared__ float fe[EMB];
  int k = blockIdx.x;
  int tid = threadIdx.x;
  if (tid < EMB) fe[tid] = emb_y[k * EMB + tid];
  __syncthreads();
  for (int r = tid; r < 3 * HIDDEN; r += 256) {
    const float* wr = W_ih + (size_t)r * 41;
    float a = b_ih[r];
    #pragma unroll
    for (int e = 0; e < EMB; e++) a += wr[1 + e] * fe[e];
    giy[(size_t)k * 1536 + r] = a;
  }
}

// W_hh -> 2 fp16 split planes: Wr[sp][jb*96 + g*32 + jl][k], row = g*512+jb*32+jl
__global__ __launch_bounds__(256) void wsplit_kernel(
    const float* __restrict__ W_hh, unsigned short* __restrict__ Wr) {
  int row = blockIdx.x;                 // 0..1535
  int g = row >> 9;
  int jg = row & 511;
  int jb = jg >> 5, jl = jg & 31;
  size_t dst = ((size_t)jb * 96 + g * 32 + jl) * 512;
  for (int k = threadIdx.x; k < 512; k += 256) {
    float w = W_hh[(size_t)row * 512 + k];
    unsigned short g0 = f2h_(w);
    float r1 = (w - h2f_(g0)) * 4096.0f;
    unsigned short g1 = f2h_(r1);
    Wr[dst + k] = g0;
    Wr[WPLANE + dst + k] = g1;
  }
}

// broadcast sT rows into h2[2][8192][512]
__global__ __launch_bounds__(128) void h2bcast_kernel(
    const unsigned short* __restrict__ sT, unsigned short* __restrict__ h2) {
  int row = blockIdx.x;
  int tid = threadIdx.x;
  int sp = tid >> 6, c = tid & 63;
  ((uint4*)(h2 + (size_t)sp * HPLANE + (size_t)row * 512))[c] =
      ((const uint4*)(sT + sp * 512))[c];
}

// ---------------------------------------------------------------------------
// Persistent encoder GRU (r12, proven): tagged single-hop exchange, padded
// LDS (stride 68). Block 0 writes the fp16-split sT directly (hsplit folded).
// ---------------------------------------------------------------------------
__device__ __forceinline__ int hpad_(int j) { return (j >> 6) * 68 + (j & 63); }

__global__ __launch_bounds__(256) void enc_gru_kernel(
    const float* __restrict__ enc_gi, const float* __restrict__ W_hh,
    const float* __restrict__ b_hh, unsigned long long* __restrict__ gh2,
    unsigned short* __restrict__ sT) {
  __shared__ __align__(16) float hsb[2][544];
  int tid = threadIdx.x;
  int gtid = blockIdx.x * 256 + tid;
  int row = gtid >> 3;
  int sub = gtid & 7;

  float w[64];
  const float* wp = W_hh + (size_t)row * HIDDEN + sub * 64;
  #pragma unroll
  for (int i = 0; i < 16; i++) {
    float4 v = *(const float4*)(wp + 4 * i);
    w[4 * i + 0] = v.x; w[4 * i + 1] = v.y; w[4 * i + 2] = v.z; w[4 * i + 3] = v.w;
  }
  for (int i = tid; i < 544; i += 256) hsb[0][i] = 0.f;
  float bhr0 = b_hh[tid],       bhz0 = b_hh[512 + tid],  bhn0 = b_hh[1024 + tid];
  float bhr1 = b_hh[256 + tid], bhz1 = b_hh[768 + tid],  bhn1 = b_hh[1280 + tid];
  __syncthreads();

  for (int t = 0; t < HIST; t++) {
    int par = t & 1;
    unsigned tag = (unsigned)(t + 1);
    const float* hc = hsb[par];
    float* hw = hsb[par ^ 1];

    const float* gi = enc_gi + (size_t)t * 1536;
    float gir0 = gi[tid],        giz0 = gi[512 + tid],  gin0 = gi[1024 + tid];
    float gir1 = gi[256 + tid],  giz1 = gi[768 + tid],  gin1 = gi[1280 + tid];

    float p = 0.0f;
    const float4* hv = (const float4*)(hc + sub * 68);
    #pragma unroll
    for (int i = 0; i < 16; i++) {
      float4 v = hv[i];
      p += w[4 * i + 0] * v.x + w[4 * i + 1] * v.y +
           w[4 * i + 2] * v.z + w[4 * i + 3] * v.w;
    }
    p += __shfl_xor(p, 1, 64);
    p += __shfl_xor(p, 2, 64);
    p += __shfl_xor(p, 4, 64);
    if (sub == 0) {
      unsigned long long pk =
          ((unsigned long long)tag << 32) | (unsigned long long)__float_as_uint(p);
      __hip_atomic_store(&gh2[par * 1536 + row], pk, __ATOMIC_RELAXED,
                         __HIP_MEMORY_SCOPE_AGENT);
    }

    const unsigned long long* g = gh2 + par * 1536;
    unsigned long long v0, v1, v2, v3, v4, v5;
    for (;;) {
      v0 = __hip_atomic_load(&g[tid],         __ATOMIC_RELAXED, __HIP_MEMORY_SCOPE_AGENT);
      v1 = __hip_atomic_load(&g[512 + tid],   __ATOMIC_RELAXED, __HIP_MEMORY_SCOPE_AGENT);
      v2 = __hip_atomic_load(&g[1024 + tid],  __ATOMIC_RELAXED, __HIP_MEMORY_SCOPE_AGENT);
      v3 = __hip_atomic_load(&g[256 + tid],   __ATOMIC_RELAXED, __HIP_MEMORY_SCOPE_AGENT);
      v4 = __hip_atomic_load(&g[768 + tid],   __ATOMIC_RELAXED, __HIP_MEMORY_SCOPE_AGENT);
      v5 = __hip_atomic_load(&g[1280 + tid],  __ATOMIC_RELAXED, __HIP_MEMORY_SCOPE_AGENT);
      if ((unsigned)(v0 >> 32) == tag && (unsigned)(v1 >> 32) == tag &&
          (unsigned)(v2 >> 32) == tag && (unsigned)(v3 >> 32) == tag &&
          (unsigned)(v4 >> 32) == tag && (unsigned)(v5 >> 32) == tag)
        break;
      __builtin_amdgcn_s_sleep(1);
    }

    {
      float ghr = __uint_as_float((unsigned)v0);
      float ghz = __uint_as_float((unsigned)v1);
      float ghn = __uint_as_float((unsigned)v2);
      float r = sigmoid_(gir0 + (ghr + bhr0));
      float z = sigmoid_(giz0 + (ghz + bhz0));
      float n = tanhf(gin0 + r * (ghn + bhn0));
      hw[hpad_(tid)] = (1.0f - z) * n + z * hc[hpad_(tid)];
    }
    {
      float ghr = __uint_as_float((unsigned)v3);
      float ghz = __uint_as_float((unsigned)v4);
      float ghn = __uint_as_float((unsigned)v5);
      float r = sigmoid_(gir1 + (ghr + bhr1));
      float z = sigmoid_(giz1 + (ghz + bhz1));
      float n = tanhf(gin1 + r * (ghn + bhn1));
      hw[hpad_(tid + 256)] = (1.0f - z) * n + z * hc[hpad_(tid + 256)];
    }
    __syncthreads();
  }
  // fused hsplit: block 0 writes fp16-split planes of final h (hsb[0])
  if (blockIdx.x == 0) {
    #pragma unroll
    for (int r = 0; r < 2; r++) {
      int j = tid + r * 256;
      float v = hsb[0][hpad_(j)];
      unsigned short f0 = f2h_(v);
      float r1 = (v - h2f_(f0)) * 4096.0f;
      sT[j] = f0;
      sT[512 + j] = f2h_(r1);
    }
  }
}

// head prologue: bit-identical to r12 dec_head math; redundant per block.
__device__ void head_prologue_(
    int mb, int jb, int tid, int kk, const float* __restrict__ partials_prev,
    const float* __restrict__ b_df, const float* __restrict__ b_loc,
    const float* __restrict__ b_sc, const float* __restrict__ scale_p,
    float* __restrict__ out, float* __restrict__ tgLds) {
  #pragma clang fp contract(off)
  if (tid < 128) {
    int s = mb * 128 + tid;
    const float* pp = partials_prev + (size_t)s * 48;
    float adf = 0.f, alo = 0.f, asc = 0.f;
    #pragma unroll
    for (int jbx = 0; jbx < 16; jbx++) {
      adf += pp[jbx * 3 + 0];
      alo += pp[jbx * 3 + 1];
      asc += pp[jbx * 3 + 2];
    }
    float df = 2.0f + softplus_(adf + b_df[0]);
    float loc = alo + b_loc[0];
    float sc = softplus_(asc + b_sc[0]);
    float eps = sample_t_eps_(kk, s, df);
    float smp = (loc + sc * eps) * scale_p[0];
    tgLds[tid] = smp;
    if (jb == 0) out[(size_t)s * PRED + kk] = smp;
  }
}

// ---------------------------------------------------------------------------
// Decoder GRU step via fp16 MFMA (r6 geometry: 1024 blocks x 128 rows x 96
// Wr-rows) + fused redundant head prologue. Initial A-stage done by waves
// 2-3 only (8 chunks/thread, same addresses/values) so it overlaps waves
// 0-1's head RNG. In-loop prefetch unchanged (all threads, 4 chunks).
// ---------------------------------------------------------------------------
__global__ __launch_bounds__(256, 2) void dec_fused_kernel(
    const unsigned short* __restrict__ h2_in,   // [2][8192][512] fp16
    const unsigned short* __restrict__ Wr,      // [2][16 jb][96][512] fp16
    const float* __restrict__ giy_k, const float* __restrict__ b_hh,
    const float* __restrict__ W_ih, const float* __restrict__ x, int k,
    unsigned short* __restrict__ h2_out,
    const float* __restrict__ W_df, const float* __restrict__ W_loc,
    const float* __restrict__ W_sc,
    const float* __restrict__ partials_prev, float* __restrict__ partials_out,
    const float* __restrict__ b_df, const float* __restrict__ b_loc,
    const float* __restrict__ b_sc, const float* __restrict__ scale_p,
    float* __restrict__ out) {
  __shared__ unsigned short As[2][2][128][32];   // [buf][plane][row][col]
  __shared__ float tgLds[128];
  int b_ = blockIdx.x;
  int xcd = b_ & 7, slot = b_ >> 3;          // slot 0..127
  int mb = xcd * 8 + (slot & 7);             // 0..63
  int jb = slot >> 3;                        // 0..15
  int tid = threadIdx.x;
  int lane = tid & 63;
  int wave = tid >> 6;
  int wm = wave >> 1, wn = wave & 1;
  int s0 = mb * 128;
  int q = lane >> 4, c = lane & 15;

  // initial A-stage on waves 2-3 (overlaps waves 0-1's head RNG below)
  if (tid >= 128) {
    int tloc = tid - 128;
    #pragma unroll
    for (int r = 0; r < 8; r++) {
      int a = r * 128 + tloc;
      int sp = a >> 9;
      int rem = a & 511;
      int arw = rem >> 2;
      int acl = rem & 3;
      uint4 v = *(const uint4*)(h2_in + (size_t)sp * HPLANE +
                                (size_t)(s0 + arw) * 512 + acl * 8);
      *(uint4*)&As[0][sp][arw][(acl ^ (arw & 3)) * 8] = v;
    }
  }
  // fused heads for step k-1 (waves 0-1; reads prev-parity partials)
  if (k > 0)
    head_prologue_(mb, jb, tid, k - 1, partials_prev, b_df, b_loc, b_sc,
                   scale_p, out, tgLds);
  float xlast = x[HIST - 1];

  f32x4 accm[4][3], accc[4][3];
  #pragma unroll
  for (int i = 0; i < 4; i++)
    #pragma unroll
    for (int g = 0; g < 3; g++) {
      accm[i][g] = (f32x4){0.f, 0.f, 0.f, 0.f};
      accc[i][g] = (f32x4){0.f, 0.f, 0.f, 0.f};
    }

  float hold[4][4];
  #pragma unroll
  for (int i = 0; i < 4; i++)
    #pragma unroll
    for (int r = 0; r < 4; r++) hold[i][r] = 0.f;

  // per-thread A staging map for in-loop prefetch (all threads, 4 chunks)
  int asp[4], arow[4], acol[4];
  #pragma unroll
  for (int r = 0; r < 4; r++) {
    int a = r * 256 + tid;
    asp[r] = a >> 9;
    int rem = a & 511;
    arow[r] = rem >> 2;
    acol[r] = rem & 3;
  }

  // B-frag base address (row jb*96 + g*32 + wn*16 + c, col chunk q)
  const unsigned short* Bbase =
      Wr + ((size_t)jb * 96 + wn * 16 + c) * 512 + q * 8;

  // initial B (kb=0)
  half8 Bcur[3][2];
  #pragma unroll
  for (int g = 0; g < 3; g++) {
    Bcur[g][0] = *(const half8*)(Bbase + (size_t)g * 32 * 512);
    Bcur[g][1] = *(const half8*)(Bbase + WPLANE + (size_t)g * 32 * 512);
  }
  __syncthreads();

  int cur = 0;
  for (int kbi = 0; kbi < 16; kbi++) {
    int kb = kbi * 32;
    // prefetch next A + B
    uint4 Areg[4];
    half8 Bn[3][2];
    if (kbi < 15) {
      #pragma unroll
      for (int r = 0; r < 4; r++)
        Areg[r] = *(const uint4*)(h2_in + (size_t)asp[r] * HPLANE +
                                  (size_t)(s0 + arow[r]) * 512 + kb + 32 +
                                  acol[r] * 8);
      #pragma unroll
      for (int g = 0; g < 3; g++) {
        Bn[g][0] = *(const half8*)(Bbase + (size_t)g * 32 * 512 + kb + 32);
        Bn[g][1] = *(const half8*)(Bbase + WPLANE + (size_t)g * 32 * 512 + kb + 32);
      }
    }
    // capture h_old while its k-slice sits in LDS
    if (kbi == jb) {
      int cc = wn * 16 + c;
      #pragma unroll
      for (int i = 0; i < 4; i++)
        #pragma unroll
        for (int reg = 0; reg < 4; reg++) {
          int m = wm * 64 + i * 16 + q * 4 + reg;
          int idx = (((cc >> 3) ^ (m & 3)) << 3) + (cc & 7);
          hold[i][reg] = h2f_(As[cur][0][m][idx]) +
                         h2f_(As[cur][1][m][idx]) * INV4096;
        }
    }
    // compute (MFMA order identical to r9)
    #pragma unroll
    for (int i = 0; i < 4; i++) {
      int m = wm * 64 + i * 16 + c;
      half8 a0 = *(const half8*)&As[cur][0][m][(q ^ (c & 3)) * 8];
      half8 a1 = *(const half8*)&As[cur][1][m][(q ^ (c & 3)) * 8];
      #pragma unroll
      for (int g = 0; g < 3; g++) {
        accm[i][g] = __builtin_amdgcn_mfma_f32_16x16x32_f16(a0, Bcur[g][0], accm[i][g], 0, 0, 0);
        accc[i][g] = __builtin_amdgcn_mfma_f32_16x16x32_f16(a0, Bcur[g][1], accc[i][g], 0, 0, 0);
        accc[i][g] = __builtin_amdgcn_mfma_f32_16x16x32_f16(a1, Bcur[g][0], accc[i][g], 0, 0, 0);
      }
    }
    // store prefetched A into the other buffer
    if (kbi < 15) {
      #pragma unroll
      for (int r = 0; r < 4; r++)
        *(uint4*)&As[cur ^ 1][asp[r]][arow[r]][(acol[r] ^ (arow[r] & 3)) * 8] =
            Areg[r];
      #pragma unroll
      for (int g = 0; g < 3; g++) {
        Bcur[g][0] = Bn[g][0];
        Bcur[g][1] = Bn[g][1];
      }
    }
    __syncthreads();
    cur ^= 1;
  }

  // epilogue: gates + h update + nt fp16 2-split store + head partials
  float* pb = (float*)&As[0][0][0][0];   // reuse LDS: 4*64*3 floats
  {
    int j = jb * 32 + wn * 16 + c;
    float gyr = giy_k[j], gyz = giy_k[512 + j], gyn = giy_k[1024 + j];
    float w0r = W_ih[(size_t)j * 41];
    float w0z = W_ih[(size_t)(512 + j) * 41];
    float w0n = W_ih[(size_t)(1024 + j) * 41];
    float bhr = b_hh[j], bhz = b_hh[512 + j], bhn = b_hh[1024 + j];
    float wdj = W_df[j], wlj = W_loc[j], wsj = W_sc[j];
    #pragma unroll
    for (int i = 0; i < 4; i++) {
      #pragma unroll
      for (int reg = 0; reg < 4; reg++) {
        int s = s0 + wm * 64 + i * 16 + q * 4 + reg;
        float tg = (k == 0) ? xlast : tgLds[wm * 64 + i * 16 + q * 4 + reg];
        size_t off = (size_t)s * 512 + j;
        float h_old = hold[i][reg];
        float ghr = accm[i][0][reg] + accc[i][0][reg] * INV4096;
        float ghz = accm[i][1][reg] + accc[i][1][reg] * INV4096;
        float ghn = accm[i][2][reg] + accc[i][2][reg] * INV4096;
        float gr = (gyr + w0r * tg) + (ghr + bhr);
        float gz = (gyz + w0z * tg) + (ghz + bhz);
        float gn_i = gyn + w0n * tg;
        float gn_h = ghn + bhn;
        float r_ = sigmoid_(gr);
        float z_ = sigmoid_(gz);
        float n_ = tanhf(gn_i + r_ * gn_h);
        float hn = (1.0f - z_) * n_ + z_ * h_old;
        unsigned short f0 = f2h_(hn);
        float r1 = (hn - h2f_(f0)) * 4096.0f;
        __builtin_nontemporal_store(f0, &h2_out[off]);
        __builtin_nontemporal_store(f2h_(r1), &h2_out[HPLANE + off]);
        // head partial products (exact fp32 h), reduce over the 16 c-lanes
        float vd = hn * wdj, vl = hn * wlj, vs = hn * wsj;
        #pragma unroll
        for (int o = 1; o < 16; o <<= 1) {
          vd += __shfl_xor(vd, o, 64);
          vl += __shfl_xor(vl, o, 64);
          vs += __shfl_xor(vs, o, 64);
        }
        if (c == 0) {
          int sl = i * 16 + q * 4 + reg;               // 0..63
          int bix = ((wm * 2 + wn) * 64 + sl) * 3;
          pb[bix + 0] = vd; pb[bix + 1] = vl; pb[bix + 2] = vs;
        }
      }
    }
  }
  __syncthreads();
  // cross-wn add (fixed order: wn0 + wn1) + global partial store
  if (tid < 128) {
    int wmh = tid >> 6, sl = tid & 63;
    int ia = (wmh * 2 + 0) * 192 + sl * 3;
    int ib = ia + 192;
    int s = s0 + wmh * 64 + sl;
    size_t pofs = (size_t)s * 48 + jb * 3;
    partials_out[pofs + 0] = pb[ia + 0] + pb[ib + 0];
    partials_out[pofs + 1] = pb[ia + 1] + pb[ib + 1];
    partials_out[pofs + 2] = pb[ia + 2] + pb[ib + 2];
  }
}

// final heads (k = PRED-1): same math as head prologue, writes out only.
__global__ __launch_bounds__(64) void dec_head_final(
    const float* __restrict__ partials, const float* __restrict__ b_df,
    const float* __restrict__ b_loc, const float* __restrict__ b_sc,
    const float* __restrict__ scale_p, float* __restrict__ out) {
  #pragma clang fp contract(off)
  int s = blockIdx.x * 64 + threadIdx.x;
  const float* p = partials + (size_t)s * 48;
  float adf = 0.f, alo = 0.f, asc = 0.f;
  #pragma unroll
  for (int jb = 0; jb < 16; jb++) {
    adf += p[jb * 3 + 0];
    alo += p[jb * 3 + 1];
    asc += p[jb * 3 + 2];
  }
  float df = 2.0f + softplus_(adf + b_df[0]);
  float loc = alo + b_loc[0];
  float sc = softplus_(asc + b_sc[0]);
  float eps = sample_t_eps_(PRED - 1, s, df);
  float smp = (loc + sc * eps) * scale_p[0];
  out[(size_t)s * PRED + (PRED - 1)] = smp;
}

// ------------------------------- launcher ----------------------------------
extern "C" void kernel_launch(void* const* d_in, const int* in_sizes, int n_in,
                              void* d_out, int out_size, void* d_ws, size_t ws_size,
                              hipStream_t stream) {
  const float* x      = (const float*)d_in[0];
  const float* x_mark = (const float*)d_in[1];
  const float* y_mark = (const float*)d_in[2];
  const float* W_emb  = (const float*)d_in[4];
  const float* b_emb  = (const float*)d_in[5];
  const float* W_ih   = (const float*)d_in[6];
  const float* W_hh   = (const float*)d_in[7];
  const float* b_ih   = (const float*)d_in[8];
  const float* b_hh   = (const float*)d_in[9];
  const float* W_df   = (const float*)d_in[10];
  const float* b_df   = (const float*)d_in[11];
  const float* W_loc  = (const float*)d_in[12];
  const float* b_loc  = (const float*)d_in[13];
  const float* W_sc   = (const float*)d_in[14];
  const float* b_sc   = (const float*)d_in[15];
  float* out = (float*)d_out;

  float* w = (float*)d_ws;
  unsigned short* h2_a = (unsigned short*)(w);                 // 2*8192*512 sh
  unsigned short* h2_b = (unsigned short*)(w + 4194304);       // 2*8192*512 sh
  unsigned short* Wr   = (unsigned short*)(w + 8388608);       // 2*1536*512 sh
  float* enc_gi = w + 9175040;              // 336*1536 (dead after encoder)
  float* giy    = w + 9691136;              // 48*1536
  float* tfe    = w + 9764864;              // 336*40
  float* emb_y  = w + 9778304;              // 48*40
  unsigned long long* gh2 = (unsigned long long*)(w + 9780224); // 2*1536 u64
  unsigned short* sT = (unsigned short*)(w + 9786880);  // 2*512 sh
  float* scale_p = w + 9795584;             // 1
  float* partials0 = w + 9795588;           // 8192*48 floats (~1.57 MB)
  float* partials1 = enc_gi;                // aliases dead enc_gi (2.06 MB)

  prep_kernel<<<1, 256, 0, stream>>>(x, x_mark, y_mark, W_emb, b_emb,
                                     scale_p, tfe, emb_y, gh2);
  enc_gi_kernel<<<HIST, 256, 0, stream>>>(x, tfe, W_ih, b_ih, scale_p, enc_gi);
  giy_kernel<<<PRED, 256, 0, stream>>>(emb_y, W_ih, b_ih, giy);
  wsplit_kernel<<<1536, 256, 0, stream>>>(W_hh, Wr);
  enc_gru_kernel<<<ENC_BLOCKS, 256, 0, stream>>>(enc_gi, W_hh, b_hh, gh2, sT);
  h2bcast_kernel<<<S_N, 128, 0, stream>>>(sT, h2_a);

  for (int k = 0; k < PRED; k++) {
    const unsigned short* h_in = (k & 1) ? h2_b : h2_a;
    unsigned short* h_o = (k & 1) ? h2_a : h2_b;
    const float* pprev = (k & 1) ? partials0 : partials1;  // (k-1)&1 parity
    float* pcur = (k & 1) ? partials1 : partials0;         // k&1 parity
    dec_fused_kernel<<<1024, 256, 0, stream>>>(
        h_in, Wr, giy + (size_t)k * 1536, b_hh, W_ih, x, k, h_o,
        W_df, W_loc, W_sc, pprev, pcur, b_df, b_loc, b_sc, scale_p, out);
  }
  // final column: heads for k = PRED-1 (partials parity 47&1 == 1)
  dec_head_final<<<S_N / 64, 64, 0, stream>>>(partials1, b_df, b_loc, b_sc,
                                              scale_p, out);
}

// Round 10
// 4545.318 us; speedup vs baseline: 1.4297x; 1.1189x over previous
//
#include <hip/hip_runtime.h>
#include <cmath>

// ---------------------------------------------------------------------------
// DeepAR sampling on MI355X. Round 19: decoder B-dedup via LDS.
// Traffic accounting (no clean dec counters available; hand-derived):
// per step A re-read 16x (268 MB) + B duplicated 2x across wm waves (384 MB)
// = 652 MB through per-XCD L2 (ws 5.1 MB > 4 MB -> IC thrash); per-iter BW
// model ~2800 cy vs observed 12.6K cy/iter -> decoder is L2-BW + thrash
// bound (MFMA floor only 18.6 us/step). r16's regression is consistent
// (halved Mt -> B doubled -> +30 us/step).
// NEW: stage per-kbi B tile (96x32x2 planes = 12 KB) in double-buffered LDS,
// loaded once per block (dedup across wm): B traffic 384->192 MB/step (-30%
// total). Same values, same MFMA order -> bit-identical. Cost: LDS 57.9 KB
// -> 2 blocks/CU (VGPR -48, no spill risk; occupancy now LDS-capped).
// Clean test of the BW-bound theory; revert to r6 if latency-bound.
// Encoder/prep unchanged (r12 + fused hsplit from r18). Fused heads kept
// (r6 style: all-thread A init; r17 wave-split was neutral, dropped).
// ---------------------------------------------------------------------------

#define JAX_PARTITIONABLE 1

#define HIDDEN 512
#define EMB 40
#define HIST 336
#define PRED 48
#define S_N 8192
#define ENC_BLOCKS 48

#define HPLANE (8192 * 512)     // shorts per h split plane
#define WPLANE (1536 * 512)     // shorts per W split plane
#define INV4096 (1.0f / 4096.0f)

typedef __attribute__((ext_vector_type(8))) _Float16 half8;
typedef __attribute__((ext_vector_type(4))) float f32x4;

// ------------------------------- threefry ----------------------------------
struct KeyPair { unsigned a, b; };

__device__ __forceinline__ unsigned rotl32_(unsigned v, unsigned s) {
  return (v << s) | (v >> (32u - s));
}

__device__ __forceinline__ KeyPair tf2x32(KeyPair k, unsigned x0, unsigned x1) {
  unsigned ks0 = k.a, ks1 = k.b, ks2 = ks0 ^ ks1 ^ 0x1BD11BDAu;
  x0 += ks0; x1 += ks1;
#define TF_R(r) { x0 += x1; x1 = rotl32_(x1, r); x1 ^= x0; }
  TF_R(13u) TF_R(15u) TF_R(26u) TF_R(6u)  x0 += ks1; x1 += ks2 + 1u;
  TF_R(17u) TF_R(29u) TF_R(16u) TF_R(24u) x0 += ks2; x1 += ks0 + 2u;
  TF_R(13u) TF_R(15u) TF_R(26u) TF_R(6u)  x0 += ks0; x1 += ks1 + 3u;
  TF_R(17u) TF_R(29u) TF_R(16u) TF_R(24u) x0 += ks1; x1 += ks2 + 4u;
  TF_R(13u) TF_R(15u) TF_R(26u) TF_R(6u)  x0 += ks2; x1 += ks0 + 5u;
#undef TF_R
  KeyPair r; r.a = x0; r.b = x1; return r;
}

__device__ __forceinline__ void split2_(KeyPair key, KeyPair& r0, KeyPair& r1) {
#if JAX_PARTITIONABLE
  r0 = tf2x32(key, 0u, 0u);
  r1 = tf2x32(key, 0u, 1u);
#else
  KeyPair p0 = tf2x32(key, 0u, 2u);
  KeyPair p1 = tf2x32(key, 1u, 3u);
  r0.a = p0.a; r0.b = p1.a;
  r1.a = p0.b; r1.b = p1.b;
#endif
}

__device__ __forceinline__ void split3_(KeyPair key, KeyPair& r0, KeyPair& r1, KeyPair& r2) {
#if JAX_PARTITIONABLE
  r0 = tf2x32(key, 0u, 0u);
  r1 = tf2x32(key, 0u, 1u);
  r2 = tf2x32(key, 0u, 2u);
#else
  KeyPair p0 = tf2x32(key, 0u, 3u);
  KeyPair p1 = tf2x32(key, 1u, 4u);
  KeyPair p2 = tf2x32(key, 2u, 5u);
  r0.a = p0.a; r0.b = p1.a;
  r1.a = p2.a; r1.b = p0.b;
  r2.a = p1.b; r2.b = p2.b;
#endif
}

__device__ __forceinline__ unsigned scalar_bits_(KeyPair key) {
#if JAX_PARTITIONABLE
  KeyPair p = tf2x32(key, 0u, 0u);
  return p.a ^ p.b;
#else
  return tf2x32(key, 0u, 0u).a;
#endif
}

__device__ __forceinline__ unsigned batch_bits_8192_(KeyPair key, int s) {
#if JAX_PARTITIONABLE
  KeyPair p = tf2x32(key, 0u, (unsigned)s);
  return p.a ^ p.b;
#else
  if (s < 4096) return tf2x32(key, (unsigned)s, (unsigned)(4096 + s)).a;
  return tf2x32(key, (unsigned)(s - 4096), (unsigned)s).b;
#endif
}

__device__ __forceinline__ KeyPair subkey_of_8192_(KeyPair key, int s) {
#if JAX_PARTITIONABLE
  return tf2x32(key, 0u, (unsigned)s);
#else
  KeyPair r;
  if (s < 4096) {
    r.a = tf2x32(key, (unsigned)(2 * s),     (unsigned)(8192 + 2 * s)).a;
    r.b = tf2x32(key, (unsigned)(2 * s + 1), (unsigned)(8192 + 2 * s + 1)).a;
  } else {
    int m = 2 * s - 8192;
    r.a = tf2x32(key, (unsigned)m,       (unsigned)(m + 8192)).b;
    r.b = tf2x32(key, (unsigned)(m + 1), (unsigned)(m + 1 + 8192)).b;
  }
  return r;
#endif
}

// ------------------------- fp32 numerics (XLA-matched) ---------------------
__device__ __forceinline__ float acc_logf_(float x) {
  return (float)log((double)x);
}
__device__ __forceinline__ float acc_expf_(float x) {
  return (float)exp((double)x);
}

__device__ __forceinline__ float bits_to_uniform01_(unsigned bits) {
  return __uint_as_float((bits >> 9) | 0x3F800000u) - 1.0f;
}

__device__ __forceinline__ float xla_log1pf_(float t) {
  #pragma clang fp contract(off)
  float small_ = (1.0f + (-0.5f) * t) * t;
  float large_ = acc_logf_(t + 1.0f);
  return (fabsf(t) < 1e-4f) ? small_ : large_;
}

__device__ float xla_erfinv_(float x) {
  #pragma clang fp contract(off)
  float w = -xla_log1pf_(-(x * x));
  float p;
  if (w < 5.0f) {
    float ww = w - 2.5f;
    p = 2.81022636e-08f;
    p = 3.43273939e-07f + p * ww;
    p = -3.5233877e-06f + p * ww;
    p = -4.39150654e-06f + p * ww;
    p = 0.00021858087f + p * ww;
    p = -0.00125372503f + p * ww;
    p = -0.00417768164f + p * ww;
    p = 0.246640727f + p * ww;
    p = 1.50140941f + p * ww;
  } else {
    float ww = sqrtf(w) - 3.0f;
    p = -0.000200214257f;
    p = 0.000100950558f + p * ww;
    p = 0.00134934322f + p * ww;
    p = -0.00367342844f + p * ww;
    p = 0.00573950773f + p * ww;
    p = -0.0076224613f + p * ww;
    p = 0.00943887047f + p * ww;
    p = 1.00167406f + p * ww;
    p = 2.83297682f + p * ww;
  }
  return p * x;
}

__device__ float bits_to_normal_(unsigned bits) {
  #pragma clang fp contract(off)
  const float lo = __uint_as_float(0xBF7FFFFFu);
  float f = bits_to_uniform01_(bits);
  float u = f * 2.0f + lo;
  u = fmaxf(lo, u);
  return __uint_as_float(0x3FB504F3u) * xla_erfinv_(u);
}

__device__ __forceinline__ float softplus_(float x) {
  #pragma clang fp contract(off)
  float amax = fmaxf(x, 0.0f);
  float e = acc_expf_(-fabsf(x));
  return amax + xla_log1pf_(e);
}

__device__ __forceinline__ float sigmoid_(float v) { return 1.0f / (1.0f + expf(-v)); }

// fp16 split helpers (round-to-nearest-even via cast)
__device__ __forceinline__ unsigned short f2h_(float f) {
  _Float16 h = (_Float16)f;
  return __builtin_bit_cast(unsigned short, h);
}
__device__ __forceinline__ float h2f_(unsigned short b) {
  return (float)__builtin_bit_cast(_Float16, b);
}

// ------------------------- gamma / student-t sampler -----------------------
__device__ float gamma_sample_(KeyPair gkey, float alpha) {
  #pragma clang fp contract(off)
  const float third = 0.33333334f;
  float d = alpha - third;
  float c = third / sqrtf(d);
  KeyPair key, boost_sub;
  split2_(gkey, key, boost_sub);
  (void)boost_sub;
  float X = 0.0f, V = 1.0f, U = 2.0f;
  for (int guard = 0; guard < 1024; guard++) {
    float X2 = X * X;
    float sq = 1.0f - 0.0331f * (X2 * X2);
    bool cont = false;
    if (U >= sq) {
      float lhs = acc_logf_(U);
      float rhs = (X * 0.5f) + (d * ((1.0f - V) + acc_logf_(V)));
      cont = (lhs >= rhs);
    }
    if (!cont) break;
    KeyPair nkey, xkey, Ukey;
    split3_(key, nkey, xkey, Ukey);
    key = nkey;
    float x, v;
    KeyPair kk = xkey;
    do {
      KeyPair knew, sub;
      split2_(kk, knew, sub);
      kk = knew;
      x = bits_to_normal_(scalar_bits_(sub));
      v = 1.0f + x * c;
    } while (v <= 0.0f);
    X = x * x;
    V = (v * v) * v;
    U = bits_to_uniform01_(scalar_bits_(Ukey));
  }
  return d * V;
}

__device__ float sample_t_eps_(int k, int s, float df) {
  #pragma clang fp contract(off)
  KeyPair base; base.a = 0u; base.b = 42u;
  KeyPair tkey = tf2x32(base, 0u, (unsigned)k);
  KeyPair key_n, key_g;
  split2_(tkey, key_n, key_g);
  float n = bits_to_normal_(batch_bits_8192_(key_n, s));
  KeyPair gkey = subkey_of_8192_(key_g, s);
  float half_df = df * 0.5f;
  float g = gamma_sample_(gkey, half_df);
  return n * sqrtf(half_df / g);
}

// ------------------------------- kernels -----------------------------------

__global__ __launch_bounds__(256) void prep_kernel(
    const float* __restrict__ x, const float* __restrict__ x_mark,
    const float* __restrict__ y_mark, const float* __restrict__ W_emb,
    const float* __restrict__ b_emb, float* __restrict__ scale_p,
    float* __restrict__ tfe, float* __restrict__ emb_y,
    unsigned long long* __restrict__ gh2) {
  __shared__ float xs[HIST];
  int tid = threadIdx.x;
  for (int i = tid; i < HIST; i += 256) xs[i] = fabsf(x[i]);
  __syncthreads();
  if (tid == 0) {
    float s = 0.0f;
    for (int t = 0; t < HIST; t++) s += xs[t];
    float m = s / 336.0f;
    scale_p[0] = fmaxf(m, 1e-5f);
  }
  // zero tagged gh exchange buffer (both parities) -> re-poison safe
  for (int i = tid; i < 2 * 1536; i += 256) gh2[i] = 0ull;
  for (int idx = tid; idx < HIST * EMB; idx += 256) {
    int t = idx / EMB, e = idx % EMB;
    float a = b_emb[e];
    for (int f = 0; f < 4; f++) a += x_mark[t * 4 + f] * W_emb[e * 4 + f];
    tfe[idx] = a;
  }
  for (int idx = tid; idx < PRED * EMB; idx += 256) {
    int kk = idx / EMB, e = idx % EMB;
    float a = b_emb[e];
    for (int f = 0; f < 4; f++) a += y_mark[kk * 4 + f] * W_emb[e * 4 + f];
    emb_y[idx] = a;
  }
}

__global__ __launch_bounds__(256) void enc_gi_kernel(
    const float* __restrict__ x, const float* __restrict__ tfe,
    const float* __restrict__ W_ih, const float* __restrict__ b_ih,
    const float* __restrict__ scale_p, float* __restrict__ enc_gi) {
  __shared__ float fe[EMB];
  __shared__ float xs_s;
  int t = blockIdx.x;
  int tid = threadIdx.x;
  if (tid < EMB) fe[tid] = tfe[t * EMB + tid];
  if (tid == 0) xs_s = x[t] / scale_p[0];
  __syncthreads();
  float xs = xs_s;
  for (int r = tid; r < 3 * HIDDEN; r += 256) {
    const float* wr = W_ih + (size_t)r * 41;
    float a = b_ih[r] + wr[0] * xs;
    #pragma unroll
    for (int e = 0; e < EMB; e++) a += wr[1 + e] * fe[e];
    enc_gi[(size_t)t * 1536 + r] = a;
  }
}

__global__ __launch_bounds__(256) void giy_kernel(
    const float* __restrict__ emb_y, const float* __restrict__ W_ih,
    const float* __restrict__ b_ih, float* __restrict__ giy) {
  __shared__ float fe[EMB];
  int k = blockIdx.x;
  int tid = threadIdx.x;
  if (tid < EMB) fe[tid] = emb_y[k * EMB + tid];
  __syncthreads();
  for (int r = tid; r < 3 * HIDDEN; r += 256) {
    const float* wr = W_ih + (size_t)r * 41;
    float a = b_ih[r];
    #pragma unroll
    for (int e = 0; e < EMB; e++) a += wr[1 + e] * fe[e];
    giy[(size_t)k * 1536 + r] = a;
  }
}

// W_hh -> 2 fp16 split planes: Wr[sp][jb*96 + g*32 + jl][k], row = g*512+jb*32+jl
__global__ __launch_bounds__(256) void wsplit_kernel(
    const float* __restrict__ W_hh, unsigned short* __restrict__ Wr) {
  int row = blockIdx.x;                 // 0..1535
  int g = row >> 9;
  int jg = row & 511;
  int jb = jg >> 5, jl = jg & 31;
  size_t dst = ((size_t)jb * 96 + g * 32 + jl) * 512;
  for (int k = threadIdx.x; k < 512; k += 256) {
    float w = W_hh[(size_t)row * 512 + k];
    unsigned short g0 = f2h_(w);
    float r1 = (w - h2f_(g0)) * 4096.0f;
    unsigned short g1 = f2h_(r1);
    Wr[dst + k] = g0;
    Wr[WPLANE + dst + k] = g1;
  }
}

// broadcast sT rows into h2[2][8192][512]
__global__ __launch_bounds__(128) void h2bcast_kernel(
    const unsigned short* __restrict__ sT, unsigned short* __restrict__ h2) {
  int row = blockIdx.x;
  int tid = threadIdx.x;
  int sp = tid >> 6, c = tid & 63;
  ((uint4*)(h2 + (size_t)sp * HPLANE + (size_t)row * 512))[c] =
      ((const uint4*)(sT + sp * 512))[c];
}

// ---------------------------------------------------------------------------
// Persistent encoder GRU (r12, proven): tagged single-hop exchange, padded
// LDS (stride 68). Block 0 writes the fp16-split sT directly (hsplit folded).
// ---------------------------------------------------------------------------
__device__ __forceinline__ int hpad_(int j) { return (j >> 6) * 68 + (j & 63); }

__global__ __launch_bounds__(256) void enc_gru_kernel(
    const float* __restrict__ enc_gi, const float* __restrict__ W_hh,
    const float* __restrict__ b_hh, unsigned long long* __restrict__ gh2,
    unsigned short* __restrict__ sT) {
  __shared__ __align__(16) float hsb[2][544];
  int tid = threadIdx.x;
  int gtid = blockIdx.x * 256 + tid;
  int row = gtid >> 3;
  int sub = gtid & 7;

  float w[64];
  const float* wp = W_hh + (size_t)row * HIDDEN + sub * 64;
  #pragma unroll
  for (int i = 0; i < 16; i++) {
    float4 v = *(const float4*)(wp + 4 * i);
    w[4 * i + 0] = v.x; w[4 * i + 1] = v.y; w[4 * i + 2] = v.z; w[4 * i + 3] = v.w;
  }
  for (int i = tid; i < 544; i += 256) hsb[0][i] = 0.f;
  float bhr0 = b_hh[tid],       bhz0 = b_hh[512 + tid],  bhn0 = b_hh[1024 + tid];
  float bhr1 = b_hh[256 + tid], bhz1 = b_hh[768 + tid],  bhn1 = b_hh[1280 + tid];
  __syncthreads();

  for (int t = 0; t < HIST; t++) {
    int par = t & 1;
    unsigned tag = (unsigned)(t + 1);
    const float* hc = hsb[par];
    float* hw = hsb[par ^ 1];

    const float* gi = enc_gi + (size_t)t * 1536;
    float gir0 = gi[tid],        giz0 = gi[512 + tid],  gin0 = gi[1024 + tid];
    float gir1 = gi[256 + tid],  giz1 = gi[768 + tid],  gin1 = gi[1280 + tid];

    float p = 0.0f;
    const float4* hv = (const float4*)(hc + sub * 68);
    #pragma unroll
    for (int i = 0; i < 16; i++) {
      float4 v = hv[i];
      p += w[4 * i + 0] * v.x + w[4 * i + 1] * v.y +
           w[4 * i + 2] * v.z + w[4 * i + 3] * v.w;
    }
    p += __shfl_xor(p, 1, 64);
    p += __shfl_xor(p, 2, 64);
    p += __shfl_xor(p, 4, 64);
    if (sub == 0) {
      unsigned long long pk =
          ((unsigned long long)tag << 32) | (unsigned long long)__float_as_uint(p);
      __hip_atomic_store(&gh2[par * 1536 + row], pk, __ATOMIC_RELAXED,
                         __HIP_MEMORY_SCOPE_AGENT);
    }

    const unsigned long long* g = gh2 + par * 1536;
    unsigned long long v0, v1, v2, v3, v4, v5;
    for (;;) {
      v0 = __hip_atomic_load(&g[tid],         __ATOMIC_RELAXED, __HIP_MEMORY_SCOPE_AGENT);
      v1 = __hip_atomic_load(&g[512 + tid],   __ATOMIC_RELAXED, __HIP_MEMORY_SCOPE_AGENT);
      v2 = __hip_atomic_load(&g[1024 + tid],  __ATOMIC_RELAXED, __HIP_MEMORY_SCOPE_AGENT);
      v3 = __hip_atomic_load(&g[256 + tid],   __ATOMIC_RELAXED, __HIP_MEMORY_SCOPE_AGENT);
      v4 = __hip_atomic_load(&g[768 + tid],   __ATOMIC_RELAXED, __HIP_MEMORY_SCOPE_AGENT);
      v5 = __hip_atomic_load(&g[1280 + tid],  __ATOMIC_RELAXED, __HIP_MEMORY_SCOPE_AGENT);
      if ((unsigned)(v0 >> 32) == tag && (unsigned)(v1 >> 32) == tag &&
          (unsigned)(v2 >> 32) == tag && (unsigned)(v3 >> 32) == tag &&
          (unsigned)(v4 >> 32) == tag && (unsigned)(v5 >> 32) == tag)
        break;
      __builtin_amdgcn_s_sleep(1);
    }

    {
      float ghr = __uint_as_float((unsigned)v0);
      float ghz = __uint_as_float((unsigned)v1);
      float ghn = __uint_as_float((unsigned)v2);
      float r = sigmoid_(gir0 + (ghr + bhr0));
      float z = sigmoid_(giz0 + (ghz + bhz0));
      float n = tanhf(gin0 + r * (ghn + bhn0));
      hw[hpad_(tid)] = (1.0f - z) * n + z * hc[hpad_(tid)];
    }
    {
      float ghr = __uint_as_float((unsigned)v3);
      float ghz = __uint_as_float((unsigned)v4);
      float ghn = __uint_as_float((unsigned)v5);
      float r = sigmoid_(gir1 + (ghr + bhr1));
      float z = sigmoid_(giz1 + (ghz + bhz1));
      float n = tanhf(gin1 + r * (ghn + bhn1));
      hw[hpad_(tid + 256)] = (1.0f - z) * n + z * hc[hpad_(tid + 256)];
    }
    __syncthreads();
  }
  // fused hsplit: block 0 writes fp16-split planes of final h (hsb[0])
  if (blockIdx.x == 0) {
    #pragma unroll
    for (int r = 0; r < 2; r++) {
      int j = tid + r * 256;
      float v = hsb[0][hpad_(j)];
      unsigned short f0 = f2h_(v);
      float r1 = (v - h2f_(f0)) * 4096.0f;
      sT[j] = f0;
      sT[512 + j] = f2h_(r1);
    }
  }
}

// head prologue: bit-identical to r12 dec_head math; redundant per block.
__device__ void head_prologue_(
    int mb, int jb, int tid, int kk, const float* __restrict__ partials_prev,
    const float* __restrict__ b_df, const float* __restrict__ b_loc,
    const float* __restrict__ b_sc, const float* __restrict__ scale_p,
    float* __restrict__ out, float* __restrict__ tgLds) {
  #pragma clang fp contract(off)
  if (tid < 128) {
    int s = mb * 128 + tid;
    const float* pp = partials_prev + (size_t)s * 48;
    float adf = 0.f, alo = 0.f, asc = 0.f;
    #pragma unroll
    for (int jbx = 0; jbx < 16; jbx++) {
      adf += pp[jbx * 3 + 0];
      alo += pp[jbx * 3 + 1];
      asc += pp[jbx * 3 + 2];
    }
    float df = 2.0f + softplus_(adf + b_df[0]);
    float loc = alo + b_loc[0];
    float sc = softplus_(asc + b_sc[0]);
    float eps = sample_t_eps_(kk, s, df);
    float smp = (loc + sc * eps) * scale_p[0];
    tgLds[tid] = smp;
    if (jb == 0) out[(size_t)s * PRED + kk] = smp;
  }
}

// ---------------------------------------------------------------------------
// Decoder GRU step via fp16 MFMA (r6 geometry: 1024 blocks x 128 rows x 96
// Wr-rows) + fused redundant head prologue. NEW: B staged once per block in
// double-buffered LDS (dedup across wm waves; -192 MB/step L2 traffic).
// Same B values, same MFMA order -> bit-identical numerics.
// ---------------------------------------------------------------------------
__global__ __launch_bounds__(256, 2) void dec_fused_kernel(
    const unsigned short* __restrict__ h2_in,   // [2][8192][512] fp16
    const unsigned short* __restrict__ Wr,      // [2][16 jb][96][512] fp16
    const float* __restrict__ giy_k, const float* __restrict__ b_hh,
    const float* __restrict__ W_ih, const float* __restrict__ x, int k,
    unsigned short* __restrict__ h2_out,
    const float* __restrict__ W_df, const float* __restrict__ W_loc,
    const float* __restrict__ W_sc,
    const float* __restrict__ partials_prev, float* __restrict__ partials_out,
    const float* __restrict__ b_df, const float* __restrict__ b_loc,
    const float* __restrict__ b_sc, const float* __restrict__ scale_p,
    float* __restrict__ out) {
  __shared__ unsigned short As[2][2][128][32];   // [buf][plane][row][col]
  __shared__ unsigned short Bs[2][2][96][32];    // [buf][plane][row96][col]
  __shared__ float tgLds[128];
  int b_ = blockIdx.x;
  int xcd = b_ & 7, slot = b_ >> 3;          // slot 0..127
  int mb = xcd * 8 + (slot & 7);             // 0..63
  int jb = slot >> 3;                        // 0..15
  int tid = threadIdx.x;
  int lane = tid & 63;
  int wave = tid >> 6;
  int wm = wave >> 1, wn = wave & 1;
  int s0 = mb * 128;
  int q = lane >> 4, c = lane & 15;
  int jb96 = jb * 96;

  // fused heads for step k-1 (reads prev-parity partials; no cross-block dep)
  if (k > 0)
    head_prologue_(mb, jb, tid, k - 1, partials_prev, b_df, b_loc, b_sc,
                   scale_p, out, tgLds);
  float xlast = x[HIST - 1];

  f32x4 accm[4][3], accc[4][3];
  #pragma unroll
  for (int i = 0; i < 4; i++)
    #pragma unroll
    for (int g = 0; g < 3; g++) {
      accm[i][g] = (f32x4){0.f, 0.f, 0.f, 0.f};
      accc[i][g] = (f32x4){0.f, 0.f, 0.f, 0.f};
    }

  float hold[4][4];
  #pragma unroll
  for (int i = 0; i < 4; i++)
    #pragma unroll
    for (int r = 0; r < 4; r++) hold[i][r] = 0.f;

  // per-thread A staging map (4 chunks covering 2 planes x 128 rows x 32 cols)
  int asp[4], arow[4], acol[4];
  #pragma unroll
  for (int r = 0; r < 4; r++) {
    int a = r * 256 + tid;
    asp[r] = a >> 9;
    int rem = a & 511;
    arow[r] = rem >> 2;
    acol[r] = rem & 3;
  }
  // per-thread B staging map (3 chunks covering 2 planes x 96 rows x 32 cols)
  int bsp[3], brow[3], bqc[3];
  #pragma unroll
  for (int r = 0; r < 3; r++) {
    int ch = r * 256 + tid;
    bsp[r] = (ch >= 384) ? 1 : 0;
    int rem = ch - bsp[r] * 384;
    brow[r] = rem >> 2;
    bqc[r] = rem & 3;
  }

  // initial stage A + B (kb=0) into buffer 0
  #pragma unroll
  for (int r = 0; r < 4; r++) {
    uint4 v = *(const uint4*)(h2_in + (size_t)asp[r] * HPLANE +
                              (size_t)(s0 + arow[r]) * 512 + acol[r] * 8);
    *(uint4*)&As[0][asp[r]][arow[r]][(acol[r] ^ (arow[r] & 3)) * 8] = v;
  }
  #pragma unroll
  for (int r = 0; r < 3; r++) {
    uint4 v = *(const uint4*)(Wr + (size_t)bsp[r] * WPLANE +
                              (size_t)(jb96 + brow[r]) * 512 + bqc[r] * 8);
    *(uint4*)&Bs[0][bsp[r]][brow[r]][(bqc[r] ^ (brow[r] & 3)) * 8] = v;
  }
  __syncthreads();

  int cur = 0;
  for (int kbi = 0; kbi < 16; kbi++) {
    int kb = kbi * 32;
    // prefetch next A + B into registers
    uint4 Areg[4];
    uint4 Breg[3];
    if (kbi < 15) {
      #pragma unroll
      for (int r = 0; r < 4; r++)
        Areg[r] = *(const uint4*)(h2_in + (size_t)asp[r] * HPLANE +
                                  (size_t)(s0 + arow[r]) * 512 + kb + 32 +
                                  acol[r] * 8);
      #pragma unroll
      for (int r = 0; r < 3; r++)
        Breg[r] = *(const uint4*)(Wr + (size_t)bsp[r] * WPLANE +
                                  (size_t)(jb96 + brow[r]) * 512 + kb + 32 +
                                  bqc[r] * 8);
    }
    // capture h_old while its k-slice sits in LDS
    if (kbi == jb) {
      int cc = wn * 16 + c;
      #pragma unroll
      for (int i = 0; i < 4; i++)
        #pragma unroll
        for (int reg = 0; reg < 4; reg++) {
          int m = wm * 64 + i * 16 + q * 4 + reg;
          int idx = (((cc >> 3) ^ (m & 3)) << 3) + (cc & 7);
          hold[i][reg] = h2f_(As[cur][0][m][idx]) +
                         h2f_(As[cur][1][m][idx]) * INV4096;
        }
    }
    // B fragments from LDS (same values as r6's register path)
    half8 b0[3], b1[3];
    #pragma unroll
    for (int g = 0; g < 3; g++) {
      int rl = g * 32 + wn * 16 + c;
      b0[g] = *(const half8*)&Bs[cur][0][rl][(q ^ (c & 3)) * 8];
      b1[g] = *(const half8*)&Bs[cur][1][rl][(q ^ (c & 3)) * 8];
    }
    // compute (MFMA order identical to r9/r6)
    #pragma unroll
    for (int i = 0; i < 4; i++) {
      int m = wm * 64 + i * 16 + c;
      half8 a0 = *(const half8*)&As[cur][0][m][(q ^ (c & 3)) * 8];
      half8 a1 = *(const half8*)&As[cur][1][m][(q ^ (c & 3)) * 8];
      #pragma unroll
      for (int g = 0; g < 3; g++) {
        accm[i][g] = __builtin_amdgcn_mfma_f32_16x16x32_f16(a0, b0[g], accm[i][g], 0, 0, 0);
        accc[i][g] = __builtin_amdgcn_mfma_f32_16x16x32_f16(a0, b1[g], accc[i][g], 0, 0, 0);
        accc[i][g] = __builtin_amdgcn_mfma_f32_16x16x32_f16(a1, b0[g], accc[i][g], 0, 0, 0);
      }
    }
    // store prefetched A + B into the other buffer
    if (kbi < 15) {
      #pragma unroll
      for (int r = 0; r < 4; r++)
        *(uint4*)&As[cur ^ 1][asp[r]][arow[r]][(acol[r] ^ (arow[r] & 3)) * 8] =
            Areg[r];
      #pragma unroll
      for (int r = 0; r < 3; r++)
        *(uint4*)&Bs[cur ^ 1][bsp[r]][brow[r]][(bqc[r] ^ (brow[r] & 3)) * 8] =
            Breg[r];
    }
    __syncthreads();
    cur ^= 1;
  }

  // epilogue: gates + h update + nt fp16 2-split store + head partials
  float* pb = (float*)&As[0][0][0][0];   // reuse LDS: 4*64*3 floats
  {
    int j = jb * 32 + wn * 16 + c;
    float gyr = giy_k[j], gyz = giy_k[512 + j], gyn = giy_k[1024 + j];
    float w0r = W_ih[(size_t)j * 41];
    float w0z = W_ih[(size_t)(512 + j) * 41];
    float w0n = W_ih[(size_t)(1024 + j) * 41];
    float bhr = b_hh[j], bhz = b_hh[512 + j], bhn = b_hh[1024 + j];
    float wdj = W_df[j], wlj = W_loc[j], wsj = W_sc[j];
    #pragma unroll
    for (int i = 0; i < 4; i++) {
      #pragma unroll
      for (int reg = 0; reg < 4; reg++) {
        int s = s0 + wm * 64 + i * 16 + q * 4 + reg;
        float tg = (k == 0) ? xlast : tgLds[wm * 64 + i * 16 + q * 4 + reg];
        size_t off = (size_t)s * 512 + j;
        float h_old = hold[i][reg];
        float ghr = accm[i][0][reg] + accc[i][0][reg] * INV4096;
        float ghz = accm[i][1][reg] + accc[i][1][reg] * INV4096;
        float ghn = accm[i][2][reg] + accc[i][2][reg] * INV4096;
        float gr = (gyr + w0r * tg) + (ghr + bhr);
        float gz = (gyz + w0z * tg) + (ghz + bhz);
        float gn_i = gyn + w0n * tg;
        float gn_h = ghn + bhn;
        float r_ = sigmoid_(gr);
        float z_ = sigmoid_(gz);
        float n_ = tanhf(gn_i + r_ * gn_h);
        float hn = (1.0f - z_) * n_ + z_ * h_old;
        unsigned short f0 = f2h_(hn);
        float r1 = (hn - h2f_(f0)) * 4096.0f;
        __builtin_nontemporal_store(f0, &h2_out[off]);
        __builtin_nontemporal_store(f2h_(r1), &h2_out[HPLANE + off]);
        // head partial products (exact fp32 h), reduce over the 16 c-lanes
        float vd = hn * wdj, vl = hn * wlj, vs = hn * wsj;
        #pragma unroll
        for (int o = 1; o < 16; o <<= 1) {
          vd += __shfl_xor(vd, o, 64);
          vl += __shfl_xor(vl, o, 64);
          vs += __shfl_xor(vs, o, 64);
        }
        if (c == 0) {
          int sl = i * 16 + q * 4 + reg;               // 0..63
          int bix = ((wm * 2 + wn) * 64 + sl) * 3;
          pb[bix + 0] = vd; pb[bix + 1] = vl; pb[bix + 2] = vs;
        }
      }
    }
  }
  __syncthreads();
  // cross-wn add (fixed order: wn0 + wn1) + global partial store
  if (tid < 128) {
    int wmh = tid >> 6, sl = tid & 63;
    int ia = (wmh * 2 + 0) * 192 + sl * 3;
    int ib = ia + 192;
    int s = s0 + wmh * 64 + sl;
    size_t pofs = (size_t)s * 48 + jb * 3;
    partials_out[pofs + 0] = pb[ia + 0] + pb[ib + 0];
    partials_out[pofs + 1] = pb[ia + 1] + pb[ib + 1];
    partials_out[pofs + 2] = pb[ia + 2] + pb[ib + 2];
  }
}

// final heads (k = PRED-1): same math as head prologue, writes out only.
__global__ __launch_bounds__(64) void dec_head_final(
    const float* __restrict__ partials, const float* __restrict__ b_df,
    const float* __restrict__ b_loc, const float* __restrict__ b_sc,
    const float* __restrict__ scale_p, float* __restrict__ out) {
  #pragma clang fp contract(off)
  int s = blockIdx.x * 64 + threadIdx.x;
  const float* p = partials + (size_t)s * 48;
  float adf = 0.f, alo = 0.f, asc = 0.f;
  #pragma unroll
  for (int jb = 0; jb < 16; jb++) {
    adf += p[jb * 3 + 0];
    alo += p[jb * 3 + 1];
    asc += p[jb * 3 + 2];
  }
  float df = 2.0f + softplus_(adf + b_df[0]);
  float loc = alo + b_loc[0];
  float sc = softplus_(asc + b_sc[0]);
  float eps = sample_t_eps_(PRED - 1, s, df);
  float smp = (loc + sc * eps) * scale_p[0];
  out[(size_t)s * PRED + (PRED - 1)] = smp;
}

// ------------------------------- launcher ----------------------------------
extern "C" void kernel_launch(void* const* d_in, const int* in_sizes, int n_in,
                              void* d_out, int out_size, void* d_ws, size_t ws_size,
                              hipStream_t stream) {
  const float* x      = (const float*)d_in[0];
  const float* x_mark = (const float*)d_in[1];
  const float* y_mark = (const float*)d_in[2];
  const float* W_emb  = (const float*)d_in[4];
  const float* b_emb  = (const float*)d_in[5];
  const float* W_ih   = (const float*)d_in[6];
  const float* W_hh   = (const float*)d_in[7];
  const float* b_ih   = (const float*)d_in[8];
  const float* b_hh   = (const float*)d_in[9];
  const float* W_df   = (const float*)d_in[10];
  const float* b_df   = (const float*)d_in[11];
  const float* W_loc  = (const float*)d_in[12];
  const float* b_loc  = (const float*)d_in[13];
  const float* W_sc   = (const float*)d_in[14];
  const float* b_sc   = (const float*)d_in[15];
  float* out = (float*)d_out;

  float* w = (float*)d_ws;
  unsigned short* h2_a = (unsigned short*)(w);                 // 2*8192*512 sh
  unsigned short* h2_b = (unsigned short*)(w + 4194304);       // 2*8192*512 sh
  unsigned short* Wr   = (unsigned short*)(w + 8388608);       // 2*1536*512 sh
  float* enc_gi = w + 9175040;              // 336*1536 (dead after encoder)
  float* giy    = w + 9691136;              // 48*1536
  float* tfe    = w + 9764864;              // 336*40
  float* emb_y  = w + 9778304;              // 48*40
  unsigned long long* gh2 = (unsigned long long*)(w + 9780224); // 2*1536 u64
  unsigned short* sT = (unsigned short*)(w + 9786880);  // 2*512 sh
  float* scale_p = w + 9795584;             // 1
  float* partials0 = w + 9795588;           // 8192*48 floats (~1.57 MB)
  float* partials1 = enc_gi;                // aliases dead enc_gi (2.06 MB)

  prep_kernel<<<1, 256, 0, stream>>>(x, x_mark, y_mark, W_emb, b_emb,
                                     scale_p, tfe, emb_y, gh2);
  enc_gi_kernel<<<HIST, 256, 0, stream>>>(x, tfe, W_ih, b_ih, scale_p, enc_gi);
  giy_kernel<<<PRED, 256, 0, stream>>>(emb_y, W_ih, b_ih, giy);
  wsplit_kernel<<<1536, 256, 0, stream>>>(W_hh, Wr);
  enc_gru_kernel<<<ENC_BLOCKS, 256, 0, stream>>>(enc_gi, W_hh, b_hh, gh2, sT);
  h2bcast_kernel<<<S_N, 128, 0, stream>>>(sT, h2_a);

  for (int k = 0; k < PRED; k++) {
    const unsigned short* h_in = (k & 1) ? h2_b : h2_a;
    unsigned short* h_o = (k & 1) ? h2_a : h2_b;
    const float* pprev = (k & 1) ? partials0 : partials1;  // (k-1)&1 parity
    float* pcur = (k & 1) ? partials1 : partials0;         // k&1 parity
    dec_fused_kernel<<<1024, 256, 0, stream>>>(
        h_in, Wr, giy + (size_t)k * 1536, b_hh, W_ih, x, k, h_o,
        W_df, W_loc, W_sc, pprev, pcur, b_df, b_loc, b_sc, scale_p, out);
  }
  // final column: heads for k = PRED-1 (partials parity 47&1 == 1)
  dec_head_final<<<S_N / 64, 64, 0, stream>>>(partials1, b_df, b_loc, b_sc,
                                              scale_p, out);
}